// Round 1
// baseline (746.881 us; speedup 1.0000x reference)
//
#include <hip/hip_runtime.h>
#include <cmath>

#define L_SEQ 2304
#define NB 4
#define D_IN 64
#define DM 256
#define DI 512
#define DSTATE 32
#define XPN 80
#define NCHUNK 8
#define CHLEN 288   // L_SEQ / NCHUNK

// ---------------- prep: transposes ----------------
// x [4][64][48][48] -> xT [4][48*48][64]
__global__ __launch_bounds__(256) void k_transpose_x(const float* __restrict__ x,
                                                     float* __restrict__ xT) {
  int id = blockIdx.x * 256 + threadIdx.x;   // 589824 total
  int ic = id & 63;
  int sp = id >> 6;                          // b*2304 + pos
  int b = sp / L_SEQ, pos = sp - b * L_SEQ;
  xT[id] = x[(size_t)(b * D_IN + ic) * L_SEQ + pos];
}

// conv_w [256][64][3][3] -> wT [256][9][64]
__global__ __launch_bounds__(256) void k_transpose_w(const float* __restrict__ w,
                                                     float* __restrict__ wT) {
  int id = blockIdx.x * 256 + threadIdx.x;   // 147456 total
  int ic = id & 63;
  int rest = id >> 6;                        // oc*9 + tap
  int oc = rest / 9, tap = rest - oc * 9;
  wT[id] = w[(size_t)(oc * D_IN + ic) * 9 + tap];
}

// ---------------- conv3x3 + BN + ReLU -> seq [B][L][256] ----------------
// grid (3 wtiles, 48 y, 4 b), 256 threads (thread = oc), 16 w per thread
__global__ __launch_bounds__(256) void k_conv(
    const float* __restrict__ xT, const float* __restrict__ wT,
    const float* __restrict__ gamma, const float* __restrict__ beta,
    const float* __restrict__ mean, const float* __restrict__ var,
    float* __restrict__ seq) {
  __shared__ float xs[3][18][64];
  int w0 = blockIdx.x * 16;
  int y  = blockIdx.y;
  int b  = blockIdx.z;
  int oc = threadIdx.x;

  for (int e = threadIdx.x; e < 3 * 18 * 64; e += 256) {
    int ic = e & 63;
    int wi = (e >> 6) % 18;
    int r  = e / (18 * 64);
    int yy = y + r - 1;
    int ww = w0 + wi - 1;
    float v = 0.f;
    if (yy >= 0 && yy < 48 && ww >= 0 && ww < 48)
      v = xT[((size_t)((b * 48 + yy) * 48 + ww)) * 64 + ic];
    xs[r][wi][ic] = v;
  }
  __syncthreads();

  float acc[16];
#pragma unroll
  for (int i = 0; i < 16; i++) acc[i] = 0.f;

  for (int dh = 0; dh < 3; dh++) {
    for (int ic4 = 0; ic4 < 16; ic4++) {
      float4 xv[18];
#pragma unroll
      for (int wi = 0; wi < 18; wi++)
        xv[wi] = *(const float4*)&xs[dh][wi][ic4 * 4];
#pragma unroll
      for (int dw = 0; dw < 3; dw++) {
        float4 wq = *(const float4*)&wT[(size_t)(oc * 9 + dh * 3 + dw) * 64 + ic4 * 4];
#pragma unroll
        for (int w = 0; w < 16; w++) {
          float4 xq = xv[w + dw];
          acc[w] = fmaf(xq.x, wq.x, fmaf(xq.y, wq.y, fmaf(xq.z, wq.z, fmaf(xq.w, wq.w, acc[w]))));
        }
      }
    }
  }

  float inv = gamma[oc] * rsqrtf(var[oc] + 1e-5f);
  float shf = beta[oc] - mean[oc] * inv;
  int lbase = y * 48 + w0;
#pragma unroll
  for (int w = 0; w < 16; w++) {
    float v = fmaxf(acc[w] * inv + shf, 0.f);
    seq[((size_t)(b * L_SEQ) + lbase + w) * DM + oc] = v;
  }
}

// ---------------- generic fp32 GEMM: C[M][N] = A[M][K] * Bw[N][K]^T ----------------
template <int BM, int BN, int BK, int TM, int TN, int TRANS_OUT>
__global__ __launch_bounds__(256) void k_gemm(
    const float* __restrict__ A, const float* __restrict__ Bw,
    float* __restrict__ C, int M, int N, int K) {
  static_assert((BM / TM) * (BN / TN) == 256, "256 threads");
  __shared__ float As[BK][BM + 4];
  __shared__ float Bs[BK][BN + 4];

  const int tid = threadIdx.x;
  const int tx = tid % (BN / TN);
  const int ty = tid / (BN / TN);
  const int tn0 = tx * TN;
  const int tm0 = ty * TM;
  const int n0 = blockIdx.x * BN;
  const int m0 = blockIdx.y * BM;
  const int KQ = BK / 4;

  float acc[TM][TN];
#pragma unroll
  for (int i = 0; i < TM; i++)
#pragma unroll
    for (int j = 0; j < TN; j++) acc[i][j] = 0.f;

  for (int k0 = 0; k0 < K; k0 += BK) {
    __syncthreads();
    for (int e = tid; e < BM * KQ; e += 256) {
      int row = e / KQ, kq = e - row * KQ;
      float4 q = *(const float4*)&A[(size_t)(m0 + row) * K + k0 + kq * 4];
      As[kq * 4 + 0][row] = q.x; As[kq * 4 + 1][row] = q.y;
      As[kq * 4 + 2][row] = q.z; As[kq * 4 + 3][row] = q.w;
    }
    for (int e = tid; e < BN * KQ; e += 256) {
      int row = e / KQ, kq = e - row * KQ;
      float4 q = *(const float4*)&Bw[(size_t)(n0 + row) * K + k0 + kq * 4];
      Bs[kq * 4 + 0][row] = q.x; Bs[kq * 4 + 1][row] = q.y;
      Bs[kq * 4 + 2][row] = q.z; Bs[kq * 4 + 3][row] = q.w;
    }
    __syncthreads();

#pragma unroll
    for (int kk = 0; kk < BK; kk++) {
      float af[TM], bf[TN];
#pragma unroll
      for (int i = 0; i < TM / 4; i++) {
        float4 q = *(const float4*)&As[kk][tm0 + 4 * i];
        af[4 * i] = q.x; af[4 * i + 1] = q.y; af[4 * i + 2] = q.z; af[4 * i + 3] = q.w;
      }
      if constexpr (TN % 4 == 0) {
#pragma unroll
        for (int j = 0; j < TN / 4; j++) {
          float4 q = *(const float4*)&Bs[kk][tn0 + 4 * j];
          bf[4 * j] = q.x; bf[4 * j + 1] = q.y; bf[4 * j + 2] = q.z; bf[4 * j + 3] = q.w;
        }
      } else {
#pragma unroll
        for (int j = 0; j < TN; j++) bf[j] = Bs[kk][tn0 + j];
      }
#pragma unroll
      for (int i = 0; i < TM; i++)
#pragma unroll
        for (int j = 0; j < TN; j++) acc[i][j] = fmaf(af[i], bf[j], acc[i][j]);
    }
  }

  if constexpr (TRANS_OUT) {
    // C is [B][N][L]: m -> (b, l)
#pragma unroll
    for (int i = 0; i < TM; i++) {
      int m = m0 + tm0 + i;
      int bb = m / L_SEQ;
      int l = m - bb * L_SEQ;
#pragma unroll
      for (int j = 0; j < TN; j++)
        C[((size_t)(bb * N) + n0 + tn0 + j) * L_SEQ + l] = acc[i][j];
    }
  } else {
#pragma unroll
    for (int i = 0; i < TM; i++) {
      float* cp = &C[(size_t)(m0 + tm0 + i) * N + n0 + tn0];
      if constexpr (TN % 4 == 0) {
#pragma unroll
        for (int j = 0; j < TN; j += 4) {
          float4 q = {acc[i][j], acc[i][j + 1], acc[i][j + 2], acc[i][j + 3]};
          *(float4*)(cp + j) = q;
        }
      } else {
#pragma unroll
        for (int j = 0; j < TN; j++) cp[j] = acc[i][j];
      }
    }
  }
}

// ---------------- causal depthwise conv1d (k=4) + bias + SiLU ----------------
// grid (2304, 4), 256 threads, 2 d per thread. u = xz[..., 0:512]
__global__ __launch_bounds__(256) void k_dwconv(
    const float* __restrict__ xz, const float* __restrict__ w1,
    const float* __restrict__ b1, float* __restrict__ uAct) {
  int l = blockIdx.x;
  int b = blockIdx.y;
  int d = threadIdx.x;
#pragma unroll
  for (int half = 0; half < 2; half++, d += 256) {
    float4 wq = *(const float4*)&w1[d * 4];
    float acc = b1[d];
    if (l >= 3) acc = fmaf(xz[((size_t)(b * L_SEQ + l - 3)) * 1024 + d], wq.x, acc);
    if (l >= 2) acc = fmaf(xz[((size_t)(b * L_SEQ + l - 2)) * 1024 + d], wq.y, acc);
    if (l >= 1) acc = fmaf(xz[((size_t)(b * L_SEQ + l - 1)) * 1024 + d], wq.z, acc);
    acc = fmaf(xz[((size_t)(b * L_SEQ + l)) * 1024 + d], wq.w, acc);
    float sil = acc / (1.f + __expf(-acc));
    uAct[((size_t)(b * L_SEQ + l)) * DI + d] = sil;
  }
}

// ---------------- dt_proj + softplus -> delta [B*L][512] ----------------
// grid 1152 (8 rows each), 256 threads (2 cols each)
__global__ __launch_bounds__(256) void k_dtproj(
    const float* __restrict__ x_dbl, const float* __restrict__ dtw,
    const float* __restrict__ dtb, float* __restrict__ delta) {
  __shared__ float xs[8][16];
  int m0 = blockIdx.x * 8;
  int tid = threadIdx.x;
  if (tid < 128) {
    int r = tid >> 4, k = tid & 15;
    xs[r][k] = x_dbl[(size_t)(m0 + r) * XPN + k];
  }
  __syncthreads();
  int n = tid;
#pragma unroll
  for (int half = 0; half < 2; half++, n += 256) {
    float4 w0 = *(const float4*)&dtw[n * 16];
    float4 w1 = *(const float4*)&dtw[n * 16 + 4];
    float4 w2 = *(const float4*)&dtw[n * 16 + 8];
    float4 w3 = *(const float4*)&dtw[n * 16 + 12];
    float bias = dtb[n];
#pragma unroll
    for (int r = 0; r < 8; r++) {
      float4 x0 = *(const float4*)&xs[r][0];
      float4 x1 = *(const float4*)&xs[r][4];
      float4 x2 = *(const float4*)&xs[r][8];
      float4 x3 = *(const float4*)&xs[r][12];
      float s = bias;
      s = fmaf(w0.x, x0.x, s); s = fmaf(w0.y, x0.y, s); s = fmaf(w0.z, x0.z, s); s = fmaf(w0.w, x0.w, s);
      s = fmaf(w1.x, x1.x, s); s = fmaf(w1.y, x1.y, s); s = fmaf(w1.z, x1.z, s); s = fmaf(w1.w, x1.w, s);
      s = fmaf(w2.x, x2.x, s); s = fmaf(w2.y, x2.y, s); s = fmaf(w2.z, x2.z, s); s = fmaf(w2.w, x2.w, s);
      s = fmaf(w3.x, x3.x, s); s = fmaf(w3.y, x3.y, s); s = fmaf(w3.z, x3.z, s); s = fmaf(w3.w, x3.w, s);
      float sp = fmaxf(s, 0.f) + log1pf(expf(-fabsf(s)));
      delta[(size_t)(m0 + r) * DI + n] = sp;
    }
  }
}

// ---------------- selective scan, 3-phase chunked ----------------
// phase 1: per-chunk local scan from 0 + decay product. grid (64 dblk, 4 b, 8 chunk)
__global__ __launch_bounds__(256) void k_scan1(
    const float* __restrict__ delta, const float* __restrict__ uA,
    const float* __restrict__ x_dbl, const float* __restrict__ A_log,
    float* __restrict__ Sbuf, float* __restrict__ Pbuf) {
  int n = threadIdx.x & 31;
  int dd = threadIdx.x >> 5;
  int d = blockIdx.x * 8 + dd;
  int b = blockIdx.y;
  int c = blockIdx.z;
  float a = -__expf(A_log[d * DSTATE + n]);
  float s = 0.f, P = 1.f;
  int t0 = c * CHLEN;
  const float* dp = delta + ((size_t)(b * L_SEQ + t0)) * DI + d;
  const float* up = uA + ((size_t)(b * L_SEQ + t0)) * DI + d;
  const float* bp = x_dbl + ((size_t)(b * L_SEQ + t0)) * XPN + 16 + n;
  for (int t = 0; t < CHLEN; t++) {
    float xw = *dp; float uu = *up; float Bn = *bp;
    dp += DI; up += DI; bp += XPN;
    float dA = __expf(xw * a);
    s = fmaf(s, dA, (xw * uu) * Bn);
    P *= dA;
  }
  int gidx = (b * DI + d) * DSTATE + n;
  Sbuf[c * 65536 + gidx] = s;
  Pbuf[c * 65536 + gidx] = P;
}

// phase 2: sequential chunk combine; Sbuf becomes per-chunk INITIAL state
__global__ __launch_bounds__(256) void k_scan2(float* __restrict__ Sbuf,
                                               const float* __restrict__ Pbuf) {
  int gidx = blockIdx.x * 256 + threadIdx.x;
  float carry = 0.f;
#pragma unroll
  for (int c = 0; c < NCHUNK; c++) {
    float s = Sbuf[c * 65536 + gidx];
    float p = Pbuf[c * 65536 + gidx];
    Sbuf[c * 65536 + gidx] = carry;
    carry = fmaf(p, carry, s);
  }
}

// phase 3: re-scan with true init state, y reduce over n, fused (y+u*D)*silu(z)
__global__ __launch_bounds__(256) void k_scan3(
    const float* __restrict__ delta, const float* __restrict__ uA,
    const float* __restrict__ x_dbl, const float* __restrict__ A_log,
    const float* __restrict__ Sbuf, const float* __restrict__ xz,
    const float* __restrict__ Dv, float* __restrict__ y) {
  int n = threadIdx.x & 31;
  int dd = threadIdx.x >> 5;
  int d = blockIdx.x * 8 + dd;
  int b = blockIdx.y;
  int c = blockIdx.z;
  float a = -__expf(A_log[d * DSTATE + n]);
  int gidx = (b * DI + d) * DSTATE + n;
  float s = Sbuf[c * 65536 + gidx];
  float Dd = Dv[d];
  int t0 = c * CHLEN;
  const float* dp = delta + ((size_t)(b * L_SEQ + t0)) * DI + d;
  const float* up = uA + ((size_t)(b * L_SEQ + t0)) * DI + d;
  const float* bp = x_dbl + ((size_t)(b * L_SEQ + t0)) * XPN + 16 + n;
  const float* cp = x_dbl + ((size_t)(b * L_SEQ + t0)) * XPN + 48 + n;
  const float* zp = xz + ((size_t)(b * L_SEQ + t0)) * 1024 + 512 + d;
  float* yp = y + ((size_t)(b * L_SEQ + t0)) * DI + d;
  for (int t = 0; t < CHLEN; t++) {
    float xw = *dp; float uu = *up; float Bn = *bp; float Cn = *cp;
    dp += DI; up += DI; bp += XPN; cp += XPN;
    float dA = __expf(xw * a);
    s = fmaf(s, dA, (xw * uu) * Bn);
    float part = s * Cn;
    part += __shfl_xor(part, 16);
    part += __shfl_xor(part, 8);
    part += __shfl_xor(part, 4);
    part += __shfl_xor(part, 2);
    part += __shfl_xor(part, 1);
    if (n == 0) {
      float zv = *zp;
      float yv = (part + uu * Dd) * (zv / (1.f + __expf(-zv)));
      *yp = yv;
    }
    zp += 1024; yp += DI;
  }
}

// ---------------- launcher ----------------
extern "C" void kernel_launch(void* const* d_in, const int* in_sizes, int n_in,
                              void* d_out, int out_size, void* d_ws, size_t ws_size,
                              hipStream_t stream) {
  const float* x     = (const float*)d_in[0];
  const float* cw    = (const float*)d_in[1];
  const float* gamma = (const float*)d_in[2];
  const float* beta  = (const float*)d_in[3];
  const float* mean  = (const float*)d_in[4];
  const float* var   = (const float*)d_in[5];
  const float* ipw   = (const float*)d_in[6];
  const float* c1w   = (const float*)d_in[7];
  const float* c1b   = (const float*)d_in[8];
  const float* xpw   = (const float*)d_in[9];
  const float* dtw   = (const float*)d_in[10];
  const float* dtb   = (const float*)d_in[11];
  const float* Alog  = (const float*)d_in[12];
  const float* Dv    = (const float*)d_in[13];
  const float* opw   = (const float*)d_in[14];
  float* out = (float*)d_out;

  float* ws = (float*)d_ws;
  size_t o = 0;
  float* seq   = ws + o; o += (size_t)NB * L_SEQ * DM;        // 2,359,296
  float* xz    = ws + o; o += (size_t)NB * L_SEQ * 1024;      // 9,437,184
  float* uAct  = ws + o; o += (size_t)NB * L_SEQ * DI;        // 4,718,592
  float* x_dbl = ws + o; o += (size_t)NB * L_SEQ * XPN;       //   737,280
  float* delta = ws + o; o += (size_t)NB * L_SEQ * DI;        // 4,718,592
  float* ybuf  = ws + o; o += (size_t)NB * L_SEQ * DI;        // 4,718,592
  float* xT    = ws + o; o += (size_t)NB * L_SEQ * D_IN;      //   589,824
  float* wT    = ws + o; o += (size_t)DM * 9 * D_IN;          //   147,456
  float* Sbuf  = ws + o; o += (size_t)NCHUNK * 65536;         //   524,288
  float* Pbuf  = ws + o; o += (size_t)NCHUNK * 65536;         //   524,288

  k_transpose_x<<<2304, 256, 0, stream>>>(x, xT);
  k_transpose_w<<<576, 256, 0, stream>>>(cw, wT);
  k_conv<<<dim3(3, 48, 4), 256, 0, stream>>>(xT, wT, gamma, beta, mean, var, seq);
  k_gemm<128, 128, 16, 8, 8, 0><<<dim3(8, 72), 256, 0, stream>>>(seq, ipw, xz, 9216, 1024, 256);
  k_dwconv<<<dim3(2304, 4), 256, 0, stream>>>(xz, c1w, c1b, uAct);
  k_gemm<128, 80, 16, 8, 5, 0><<<dim3(1, 72), 256, 0, stream>>>(uAct, xpw, x_dbl, 9216, 80, 512);
  k_dtproj<<<1152, 256, 0, stream>>>(x_dbl, dtw, dtb, delta);
  k_scan1<<<dim3(64, 4, 8), 256, 0, stream>>>(delta, uAct, x_dbl, Alog, Sbuf, Pbuf);
  k_scan2<<<256, 256, 0, stream>>>(Sbuf, Pbuf);
  k_scan3<<<dim3(64, 4, 8), 256, 0, stream>>>(delta, uAct, x_dbl, Alog, Sbuf, xz, Dv, ybuf);
  k_gemm<64, 128, 16, 4, 8, 1><<<dim3(2, 144), 256, 0, stream>>>(ybuf, opw, out, 9216, 256, 512);
}

// Round 2
// 524.186 us; speedup vs baseline: 1.4248x; 1.4248x over previous
//
#include <hip/hip_runtime.h>
#include <cmath>

#define L_SEQ 2304
#define NB 4
#define D_IN 64
#define DM 256
#define DI 512
#define DSTATE 32
#define XPN 80
#define NCHUNK 64
#define CHLEN 36   // L_SEQ / NCHUNK

// ---------------- prep: transposes ----------------
// x [4][64][48][48] -> xT [4][48*48][64]
__global__ __launch_bounds__(256) void k_transpose_x(const float* __restrict__ x,
                                                     float* __restrict__ xT) {
  int id = blockIdx.x * 256 + threadIdx.x;   // 589824 total
  int ic = id & 63;
  int sp = id >> 6;                          // b*2304 + pos
  int b = sp / L_SEQ, pos = sp - b * L_SEQ;
  xT[id] = x[(size_t)(b * D_IN + ic) * L_SEQ + pos];
}

// conv_w [256][64][3][3] -> wT [256][9][64]
__global__ __launch_bounds__(256) void k_transpose_w(const float* __restrict__ w,
                                                     float* __restrict__ wT) {
  int id = blockIdx.x * 256 + threadIdx.x;   // 147456 total
  int ic = id & 63;
  int rest = id >> 6;                        // oc*9 + tap
  int oc = rest / 9, tap = rest - oc * 9;
  wT[id] = w[(size_t)(oc * D_IN + ic) * 9 + tap];
}

// ---------------- conv3x3 + BN + ReLU -> seq [B][L][256] ----------------
__global__ __launch_bounds__(256) void k_conv(
    const float* __restrict__ xT, const float* __restrict__ wT,
    const float* __restrict__ gamma, const float* __restrict__ beta,
    const float* __restrict__ mean, const float* __restrict__ var,
    float* __restrict__ seq) {
  __shared__ float xs[3][18][64];
  int w0 = blockIdx.x * 16;
  int y  = blockIdx.y;
  int b  = blockIdx.z;
  int oc = threadIdx.x;

  for (int e = threadIdx.x; e < 3 * 18 * 64; e += 256) {
    int ic = e & 63;
    int wi = (e >> 6) % 18;
    int r  = e / (18 * 64);
    int yy = y + r - 1;
    int ww = w0 + wi - 1;
    float v = 0.f;
    if (yy >= 0 && yy < 48 && ww >= 0 && ww < 48)
      v = xT[((size_t)((b * 48 + yy) * 48 + ww)) * 64 + ic];
    xs[r][wi][ic] = v;
  }
  __syncthreads();

  float acc[16];
#pragma unroll
  for (int i = 0; i < 16; i++) acc[i] = 0.f;

  for (int dh = 0; dh < 3; dh++) {
    for (int ic4 = 0; ic4 < 16; ic4++) {
      float4 xv[18];
#pragma unroll
      for (int wi = 0; wi < 18; wi++)
        xv[wi] = *(const float4*)&xs[dh][wi][ic4 * 4];
#pragma unroll
      for (int dw = 0; dw < 3; dw++) {
        float4 wq = *(const float4*)&wT[(size_t)(oc * 9 + dh * 3 + dw) * 64 + ic4 * 4];
#pragma unroll
        for (int w = 0; w < 16; w++) {
          float4 xq = xv[w + dw];
          acc[w] = fmaf(xq.x, wq.x, fmaf(xq.y, wq.y, fmaf(xq.z, wq.z, fmaf(xq.w, wq.w, acc[w]))));
        }
      }
    }
  }

  float inv = gamma[oc] * rsqrtf(var[oc] + 1e-5f);
  float shf = beta[oc] - mean[oc] * inv;
  int lbase = y * 48 + w0;
#pragma unroll
  for (int w = 0; w < 16; w++) {
    float v = fmaxf(acc[w] * inv + shf, 0.f);
    seq[((size_t)(b * L_SEQ) + lbase + w) * DM + oc] = v;
  }
}

// ---------------- generic fp32 GEMM: C[M][N] = A[M][K] * Bw[N][K]^T ----------------
template <int BM, int BN, int BK, int TM, int TN>
__global__ __launch_bounds__(256) void k_gemm(
    const float* __restrict__ A, const float* __restrict__ Bw,
    float* __restrict__ C, int M, int N, int K) {
  static_assert((BM / TM) * (BN / TN) == 256, "256 threads");
  __shared__ float As[BK][BM + 4];
  __shared__ float Bs[BK][BN + 4];

  const int tid = threadIdx.x;
  const int tx = tid % (BN / TN);
  const int ty = tid / (BN / TN);
  const int tn0 = tx * TN;
  const int tm0 = ty * TM;
  const int n0 = blockIdx.x * BN;
  const int m0 = blockIdx.y * BM;
  const int KQ = BK / 4;

  float acc[TM][TN];
#pragma unroll
  for (int i = 0; i < TM; i++)
#pragma unroll
    for (int j = 0; j < TN; j++) acc[i][j] = 0.f;

  for (int k0 = 0; k0 < K; k0 += BK) {
    __syncthreads();
    for (int e = tid; e < BM * KQ; e += 256) {
      int row = e / KQ, kq = e - row * KQ;
      float4 q = *(const float4*)&A[(size_t)(m0 + row) * K + k0 + kq * 4];
      As[kq * 4 + 0][row] = q.x; As[kq * 4 + 1][row] = q.y;
      As[kq * 4 + 2][row] = q.z; As[kq * 4 + 3][row] = q.w;
    }
    for (int e = tid; e < BN * KQ; e += 256) {
      int row = e / KQ, kq = e - row * KQ;
      float4 q = *(const float4*)&Bw[(size_t)(n0 + row) * K + k0 + kq * 4];
      Bs[kq * 4 + 0][row] = q.x; Bs[kq * 4 + 1][row] = q.y;
      Bs[kq * 4 + 2][row] = q.z; Bs[kq * 4 + 3][row] = q.w;
    }
    __syncthreads();

#pragma unroll
    for (int kk = 0; kk < BK; kk++) {
      float af[TM], bf[TN];
      if constexpr (TM % 4 == 0) {
#pragma unroll
        for (int i = 0; i < TM / 4; i++) {
          float4 q = *(const float4*)&As[kk][tm0 + 4 * i];
          af[4 * i] = q.x; af[4 * i + 1] = q.y; af[4 * i + 2] = q.z; af[4 * i + 3] = q.w;
        }
      } else {
#pragma unroll
        for (int i = 0; i < TM; i++) af[i] = As[kk][tm0 + i];
      }
      if constexpr (TN % 4 == 0) {
#pragma unroll
        for (int j = 0; j < TN / 4; j++) {
          float4 q = *(const float4*)&Bs[kk][tn0 + 4 * j];
          bf[4 * j] = q.x; bf[4 * j + 1] = q.y; bf[4 * j + 2] = q.z; bf[4 * j + 3] = q.w;
        }
      } else {
#pragma unroll
        for (int j = 0; j < TN; j++) bf[j] = Bs[kk][tn0 + j];
      }
#pragma unroll
      for (int i = 0; i < TM; i++)
#pragma unroll
        for (int j = 0; j < TN; j++) acc[i][j] = fmaf(af[i], bf[j], acc[i][j]);
    }
  }

#pragma unroll
  for (int i = 0; i < TM; i++) {
    float* cp = &C[(size_t)(m0 + tm0 + i) * N + n0 + tn0];
    if constexpr (TN % 4 == 0) {
#pragma unroll
      for (int j = 0; j < TN; j += 4) {
        float4 q = {acc[i][j], acc[i][j + 1], acc[i][j + 2], acc[i][j + 3]};
        *(float4*)(cp + j) = q;
      }
    } else {
#pragma unroll
      for (int j = 0; j < TN; j++) cp[j] = acc[i][j];
    }
  }
}

// ---------------- causal depthwise conv1d (k=4) + bias + SiLU ----------------
__global__ __launch_bounds__(256) void k_dwconv(
    const float* __restrict__ xz, const float* __restrict__ w1,
    const float* __restrict__ b1, float* __restrict__ uAct) {
  int l = blockIdx.x;
  int b = blockIdx.y;
  int d = threadIdx.x;
#pragma unroll
  for (int half = 0; half < 2; half++, d += 256) {
    float4 wq = *(const float4*)&w1[d * 4];
    float acc = b1[d];
    if (l >= 3) acc = fmaf(xz[((size_t)(b * L_SEQ + l - 3)) * 1024 + d], wq.x, acc);
    if (l >= 2) acc = fmaf(xz[((size_t)(b * L_SEQ + l - 2)) * 1024 + d], wq.y, acc);
    if (l >= 1) acc = fmaf(xz[((size_t)(b * L_SEQ + l - 1)) * 1024 + d], wq.z, acc);
    acc = fmaf(xz[((size_t)(b * L_SEQ + l)) * 1024 + d], wq.w, acc);
    float sil = acc / (1.f + __expf(-acc));
    uAct[((size_t)(b * L_SEQ + l)) * DI + d] = sil;
  }
}

// ---------------- dt_proj + softplus -> delta [B*L][512] ----------------
__global__ __launch_bounds__(256) void k_dtproj(
    const float* __restrict__ x_dbl, const float* __restrict__ dtw,
    const float* __restrict__ dtb, float* __restrict__ delta) {
  __shared__ float xs[8][16];
  int m0 = blockIdx.x * 8;
  int tid = threadIdx.x;
  if (tid < 128) {
    int r = tid >> 4, k = tid & 15;
    xs[r][k] = x_dbl[(size_t)(m0 + r) * XPN + k];
  }
  __syncthreads();
  int n = tid;
#pragma unroll
  for (int half = 0; half < 2; half++, n += 256) {
    float4 w0 = *(const float4*)&dtw[n * 16];
    float4 w1 = *(const float4*)&dtw[n * 16 + 4];
    float4 w2 = *(const float4*)&dtw[n * 16 + 8];
    float4 w3 = *(const float4*)&dtw[n * 16 + 12];
    float bias = dtb[n];
#pragma unroll
    for (int r = 0; r < 8; r++) {
      float4 x0 = *(const float4*)&xs[r][0];
      float4 x1 = *(const float4*)&xs[r][4];
      float4 x2 = *(const float4*)&xs[r][8];
      float4 x3 = *(const float4*)&xs[r][12];
      float s = bias;
      s = fmaf(w0.x, x0.x, s); s = fmaf(w0.y, x0.y, s); s = fmaf(w0.z, x0.z, s); s = fmaf(w0.w, x0.w, s);
      s = fmaf(w1.x, x1.x, s); s = fmaf(w1.y, x1.y, s); s = fmaf(w1.z, x1.z, s); s = fmaf(w1.w, x1.w, s);
      s = fmaf(w2.x, x2.x, s); s = fmaf(w2.y, x2.y, s); s = fmaf(w2.z, x2.z, s); s = fmaf(w2.w, x2.w, s);
      s = fmaf(w3.x, x3.x, s); s = fmaf(w3.y, x3.y, s); s = fmaf(w3.z, x3.z, s); s = fmaf(w3.w, x3.w, s);
      float sp = fmaxf(s, 0.f) + log1pf(expf(-fabsf(s)));
      delta[(size_t)(m0 + r) * DI + n] = sp;
    }
  }
}

// ---------------- selective scan, 3-phase chunked ----------------
// Thread owns one d with all 32 n-states in registers. No shuffles.
// Chunk decay product P[n] = exp(a[n] * sum_t delta_t) -> store only scalar sumx.
// phase 1: local scan from 0 + sum of deltas. grid (2, 4, 64) x 256 thr
__global__ __launch_bounds__(256) void k_scan1(
    const float* __restrict__ delta, const float* __restrict__ uA,
    const float* __restrict__ x_dbl, const float* __restrict__ A_log,
    float* __restrict__ Sbuf, float* __restrict__ Sumx) {
  int d = blockIdx.x * 256 + threadIdx.x;
  int b = blockIdx.y;
  int c = blockIdx.z;

  float a[DSTATE];
#pragma unroll
  for (int q = 0; q < 8; q++) {
    float4 av = *(const float4*)&A_log[d * DSTATE + 4 * q];
    a[4 * q + 0] = -__expf(av.x); a[4 * q + 1] = -__expf(av.y);
    a[4 * q + 2] = -__expf(av.z); a[4 * q + 3] = -__expf(av.w);
  }
  float s[DSTATE];
#pragma unroll
  for (int n = 0; n < DSTATE; n++) s[n] = 0.f;
  float sumx = 0.f;

  int t0 = c * CHLEN;
  const float* dp = delta + ((size_t)(b * L_SEQ + t0)) * DI + d;
  const float* up = uA + ((size_t)(b * L_SEQ + t0)) * DI + d;
  const float* bp = x_dbl + ((size_t)(b * L_SEQ + t0)) * XPN + 16;

#pragma unroll 4
  for (int t = 0; t < CHLEN; t++) {
    float xw = *dp; float uu = *up;
    float4 Bq[8];
#pragma unroll
    for (int q = 0; q < 8; q++) Bq[q] = *(const float4*)(bp + 4 * q);
    dp += DI; up += DI; bp += XPN;
    float du = xw * uu;
    sumx += xw;
#pragma unroll
    for (int q = 0; q < 8; q++) {
      s[4 * q + 0] = fmaf(s[4 * q + 0], __expf(xw * a[4 * q + 0]), du * Bq[q].x);
      s[4 * q + 1] = fmaf(s[4 * q + 1], __expf(xw * a[4 * q + 1]), du * Bq[q].y);
      s[4 * q + 2] = fmaf(s[4 * q + 2], __expf(xw * a[4 * q + 2]), du * Bq[q].z);
      s[4 * q + 3] = fmaf(s[4 * q + 3], __expf(xw * a[4 * q + 3]), du * Bq[q].w);
    }
  }

  float* sb = Sbuf + ((size_t)c * 65536) + ((size_t)(b * DI + d)) * DSTATE;
#pragma unroll
  for (int q = 0; q < 8; q++) {
    float4 v = {s[4 * q], s[4 * q + 1], s[4 * q + 2], s[4 * q + 3]};
    *(float4*)(sb + 4 * q) = v;
  }
  Sumx[c * (NB * DI) + b * DI + d] = sumx;
}

// phase 2: sequential chunk combine; Sbuf becomes per-chunk INITIAL state
__global__ __launch_bounds__(256) void k_scan2(float* __restrict__ Sbuf,
                                               const float* __restrict__ Sumx,
                                               const float* __restrict__ A_log) {
  int gidx = blockIdx.x * 256 + threadIdx.x;   // (b*DI+d)*32+n
  int bd = gidx >> 5;
  int d = bd & (DI - 1);
  int n = gidx & 31;
  float a = -__expf(A_log[d * DSTATE + n]);
  float carry = 0.f;
  for (int c = 0; c < NCHUNK; c++) {
    float s = Sbuf[(size_t)c * 65536 + gidx];
    float p = __expf(a * Sumx[c * (NB * DI) + bd]);
    Sbuf[(size_t)c * 65536 + gidx] = carry;
    carry = fmaf(p, carry, s);
  }
}

// phase 3: re-scan with true init state, in-register y dot, fused epilogue
__global__ __launch_bounds__(256) void k_scan3(
    const float* __restrict__ delta, const float* __restrict__ uA,
    const float* __restrict__ x_dbl, const float* __restrict__ A_log,
    const float* __restrict__ Sbuf, const float* __restrict__ xz,
    const float* __restrict__ Dv, float* __restrict__ y) {
  int d = blockIdx.x * 256 + threadIdx.x;
  int b = blockIdx.y;
  int c = blockIdx.z;

  float a[DSTATE];
#pragma unroll
  for (int q = 0; q < 8; q++) {
    float4 av = *(const float4*)&A_log[d * DSTATE + 4 * q];
    a[4 * q + 0] = -__expf(av.x); a[4 * q + 1] = -__expf(av.y);
    a[4 * q + 2] = -__expf(av.z); a[4 * q + 3] = -__expf(av.w);
  }
  float s[DSTATE];
  const float* sb = Sbuf + ((size_t)c * 65536) + ((size_t)(b * DI + d)) * DSTATE;
#pragma unroll
  for (int q = 0; q < 8; q++) {
    float4 v = *(const float4*)(sb + 4 * q);
    s[4 * q] = v.x; s[4 * q + 1] = v.y; s[4 * q + 2] = v.z; s[4 * q + 3] = v.w;
  }
  float Dd = Dv[d];

  int t0 = c * CHLEN;
  const float* dp = delta + ((size_t)(b * L_SEQ + t0)) * DI + d;
  const float* up = uA + ((size_t)(b * L_SEQ + t0)) * DI + d;
  const float* bp = x_dbl + ((size_t)(b * L_SEQ + t0)) * XPN + 16;
  const float* cp = x_dbl + ((size_t)(b * L_SEQ + t0)) * XPN + 48;
  const float* zp = xz + ((size_t)(b * L_SEQ + t0)) * 1024 + 512 + d;
  float* yp = y + ((size_t)(b * L_SEQ + t0)) * DI + d;

#pragma unroll 4
  for (int t = 0; t < CHLEN; t++) {
    float xw = *dp; float uu = *up; float zv = *zp;
    float4 Bq[8], Cq[8];
#pragma unroll
    for (int q = 0; q < 8; q++) Bq[q] = *(const float4*)(bp + 4 * q);
#pragma unroll
    for (int q = 0; q < 8; q++) Cq[q] = *(const float4*)(cp + 4 * q);
    dp += DI; up += DI; bp += XPN; cp += XPN; zp += 1024;
    float du = xw * uu;
    float yv = 0.f;
#pragma unroll
    for (int q = 0; q < 8; q++) {
      s[4 * q + 0] = fmaf(s[4 * q + 0], __expf(xw * a[4 * q + 0]), du * Bq[q].x);
      s[4 * q + 1] = fmaf(s[4 * q + 1], __expf(xw * a[4 * q + 1]), du * Bq[q].y);
      s[4 * q + 2] = fmaf(s[4 * q + 2], __expf(xw * a[4 * q + 2]), du * Bq[q].z);
      s[4 * q + 3] = fmaf(s[4 * q + 3], __expf(xw * a[4 * q + 3]), du * Bq[q].w);
      yv = fmaf(s[4 * q + 0], Cq[q].x, yv);
      yv = fmaf(s[4 * q + 1], Cq[q].y, yv);
      yv = fmaf(s[4 * q + 2], Cq[q].z, yv);
      yv = fmaf(s[4 * q + 3], Cq[q].w, yv);
    }
    float out = (yv + uu * Dd) * (zv / (1.f + __expf(-zv)));
    *yp = out;
    yp += DI;
  }
}

// ---------------- final transpose: [B][L][256] -> [B][256][L] ----------------
__global__ __launch_bounds__(256) void k_transpose_out(const float* __restrict__ src,
                                                       float* __restrict__ dst) {
  __shared__ float tile[32][33];
  int l0 = blockIdx.x * 32;
  int n0 = blockIdx.y * 32;
  int b = blockIdx.z;
  int tx = threadIdx.x & 31;
  int ty = threadIdx.x >> 5;   // 0..7
#pragma unroll
  for (int r = ty; r < 32; r += 8)
    tile[r][tx] = src[((size_t)(b * L_SEQ + l0 + r)) * DM + n0 + tx];
  __syncthreads();
#pragma unroll
  for (int r = ty; r < 32; r += 8)
    dst[((size_t)(b * DM + n0 + r)) * L_SEQ + l0 + tx] = tile[tx][r];
}

// ---------------- launcher ----------------
extern "C" void kernel_launch(void* const* d_in, const int* in_sizes, int n_in,
                              void* d_out, int out_size, void* d_ws, size_t ws_size,
                              hipStream_t stream) {
  const float* x     = (const float*)d_in[0];
  const float* cw    = (const float*)d_in[1];
  const float* gamma = (const float*)d_in[2];
  const float* beta  = (const float*)d_in[3];
  const float* mean  = (const float*)d_in[4];
  const float* var   = (const float*)d_in[5];
  const float* ipw   = (const float*)d_in[6];
  const float* c1w   = (const float*)d_in[7];
  const float* c1b   = (const float*)d_in[8];
  const float* xpw   = (const float*)d_in[9];
  const float* dtw   = (const float*)d_in[10];
  const float* dtb   = (const float*)d_in[11];
  const float* Alog  = (const float*)d_in[12];
  const float* Dv    = (const float*)d_in[13];
  const float* opw   = (const float*)d_in[14];
  float* out = (float*)d_out;

  float* ws = (float*)d_ws;
  size_t o = 0;
  float* seq   = ws + o; o += (size_t)NB * L_SEQ * DM;        // 2,359,296 (reused as GEMM-out scratch)
  float* xz    = ws + o; o += (size_t)NB * L_SEQ * 1024;      // 9,437,184
  float* uAct  = ws + o; o += (size_t)NB * L_SEQ * DI;        // 4,718,592
  float* x_dbl = ws + o; o += (size_t)NB * L_SEQ * XPN;       //   737,280
  float* delta = ws + o; o += (size_t)NB * L_SEQ * DI;        // 4,718,592
  float* ybuf  = ws + o; o += (size_t)NB * L_SEQ * DI;        // 4,718,592
  float* xT    = ws + o; o += (size_t)NB * L_SEQ * D_IN;      //   589,824
  float* wT    = ws + o; o += (size_t)DM * 9 * D_IN;          //   147,456
  float* Sbuf  = ws + o; o += (size_t)NCHUNK * 65536;         // 4,194,304
  float* Sumx  = ws + o; o += (size_t)NCHUNK * NB * DI;       //   131,072

  k_transpose_x<<<2304, 256, 0, stream>>>(x, xT);
  k_transpose_w<<<576, 256, 0, stream>>>(cw, wT);
  k_conv<<<dim3(3, 48, 4), 256, 0, stream>>>(xT, wT, gamma, beta, mean, var, seq);
  k_gemm<128, 128, 16, 8, 8><<<dim3(8, 72), 256, 0, stream>>>(seq, ipw, xz, 9216, 1024, 256);
  k_dwconv<<<dim3(2304, 4), 256, 0, stream>>>(xz, c1w, c1b, uAct);
  k_gemm<64, 80, 32, 4, 5><<<dim3(1, 144), 256, 0, stream>>>(uAct, xpw, x_dbl, 9216, 80, 512);
  k_dtproj<<<1152, 256, 0, stream>>>(x_dbl, dtw, dtb, delta);
  k_scan1<<<dim3(2, 4, NCHUNK), 256, 0, stream>>>(delta, uAct, x_dbl, Alog, Sbuf, Sumx);
  k_scan2<<<256, 256, 0, stream>>>(Sbuf, Sumx, Alog);
  k_scan3<<<dim3(2, 4, NCHUNK), 256, 0, stream>>>(delta, uAct, x_dbl, Alog, Sbuf, xz, Dv, ybuf);
  // out_proj into row-major scratch (reuse seq), then LDS-tiled transpose to NCHW
  k_gemm<64, 128, 16, 4, 8><<<dim3(2, 144), 256, 0, stream>>>(ybuf, opw, seq, 9216, 256, 512);
  k_transpose_out<<<dim3(72, 8, 4), 256, 0, stream>>>(seq, out);
}

// Round 3
// 511.753 us; speedup vs baseline: 1.4595x; 1.0243x over previous
//
#include <hip/hip_runtime.h>
#include <cmath>

#define L_SEQ 2304
#define NB 4
#define D_IN 64
#define DM 256
#define DI 512
#define DSTATE 32
#define XPN 80
#define NCHUNK 64
#define CHLEN 36   // L_SEQ / NCHUNK

// ---------------- prep: transposes ----------------
// x [4][64][48][48] -> xT [4][48*48][64]
__global__ __launch_bounds__(256) void k_transpose_x(const float* __restrict__ x,
                                                     float* __restrict__ xT) {
  int id = blockIdx.x * 256 + threadIdx.x;   // 589824 total
  int ic = id & 63;
  int sp = id >> 6;                          // b*2304 + pos
  int b = sp / L_SEQ, pos = sp - b * L_SEQ;
  xT[id] = x[(size_t)(b * D_IN + ic) * L_SEQ + pos];
}

// conv_w [256][64][3][3] -> wT [256][9][64]  (= [256][576] k-major, k = tap*64+ic)
__global__ __launch_bounds__(256) void k_transpose_w(const float* __restrict__ w,
                                                     float* __restrict__ wT) {
  int id = blockIdx.x * 256 + threadIdx.x;   // 147456 total
  int ic = id & 63;
  int rest = id >> 6;                        // oc*9 + tap
  int oc = rest / 9, tap = rest - oc * 9;
  wT[id] = w[(size_t)(oc * D_IN + ic) * 9 + tap];
}

// ---------------- conv3x3 + BN + ReLU as implicit GEMM ----------------
// C[9216][256] = im2col(xT)[9216][576] * wT[256][576]^T, epilogue BN+ReLU
// BM=64, BN=64, BK=32, TM=4, TN=4, grid (4, 144)
__global__ __launch_bounds__(256) void k_convgemm(
    const float* __restrict__ xT, const float* __restrict__ wT,
    const float* __restrict__ gamma, const float* __restrict__ beta,
    const float* __restrict__ mean, const float* __restrict__ var,
    float* __restrict__ seq) {
  __shared__ float As[32][68];
  __shared__ float Bs[32][68];
  const int tid = threadIdx.x;
  const int tx = tid & 15;
  const int ty = tid >> 4;
  const int tn0 = tx * 4;
  const int tm0 = ty * 4;
  const int n0 = blockIdx.x * 64;
  const int m0 = blockIdx.y * 64;

  // staging coords: e = tid (+256): row = e>>3, kq = e&7
  const int kq = tid & 7;
  const int r0 = tid >> 3;            // 0..31, second row = r0+32
  int m1 = m0 + r0, m2 = m0 + r0 + 32;
  int b1 = m1 / L_SEQ, rem1 = m1 - b1 * L_SEQ, y1 = rem1 / 48, x1 = rem1 - y1 * 48;
  int b2 = m2 / L_SEQ, rem2 = m2 - b2 * L_SEQ, y2 = rem2 / 48, x2 = rem2 - y2 * 48;

  float acc[4][4];
#pragma unroll
  for (int i = 0; i < 4; i++)
#pragma unroll
    for (int j = 0; j < 4; j++) acc[i][j] = 0.f;

  for (int k0 = 0; k0 < 576; k0 += 32) {
    int tap = k0 >> 6;
    int ic_off = (k0 & 63) + kq * 4;
    int dh = tap / 3 - 1;
    int dw = tap % 3 - 1;
    __syncthreads();
    {
      int yy = y1 + dh, ww = x1 + dw;
      float4 q = {0.f, 0.f, 0.f, 0.f};
      if ((unsigned)yy < 48u && (unsigned)ww < 48u)
        q = *(const float4*)&xT[(((size_t)(b1 * 48 + yy)) * 48 + ww) * 64 + ic_off];
      As[kq * 4 + 0][r0] = q.x; As[kq * 4 + 1][r0] = q.y;
      As[kq * 4 + 2][r0] = q.z; As[kq * 4 + 3][r0] = q.w;
    }
    {
      int yy = y2 + dh, ww = x2 + dw;
      float4 q = {0.f, 0.f, 0.f, 0.f};
      if ((unsigned)yy < 48u && (unsigned)ww < 48u)
        q = *(const float4*)&xT[(((size_t)(b2 * 48 + yy)) * 48 + ww) * 64 + ic_off];
      As[kq * 4 + 0][r0 + 32] = q.x; As[kq * 4 + 1][r0 + 32] = q.y;
      As[kq * 4 + 2][r0 + 32] = q.z; As[kq * 4 + 3][r0 + 32] = q.w;
    }
    {
      float4 q = *(const float4*)&wT[(size_t)(n0 + r0) * 576 + k0 + kq * 4];
      Bs[kq * 4 + 0][r0] = q.x; Bs[kq * 4 + 1][r0] = q.y;
      Bs[kq * 4 + 2][r0] = q.z; Bs[kq * 4 + 3][r0] = q.w;
      float4 p = *(const float4*)&wT[(size_t)(n0 + r0 + 32) * 576 + k0 + kq * 4];
      Bs[kq * 4 + 0][r0 + 32] = p.x; Bs[kq * 4 + 1][r0 + 32] = p.y;
      Bs[kq * 4 + 2][r0 + 32] = p.z; Bs[kq * 4 + 3][r0 + 32] = p.w;
    }
    __syncthreads();

#pragma unroll
    for (int kk = 0; kk < 32; kk++) {
      float4 a = *(const float4*)&As[kk][tm0];
      float4 bq = *(const float4*)&Bs[kk][tn0];
      float af[4] = {a.x, a.y, a.z, a.w};
      float bf[4] = {bq.x, bq.y, bq.z, bq.w};
#pragma unroll
      for (int i = 0; i < 4; i++)
#pragma unroll
        for (int j = 0; j < 4; j++) acc[i][j] = fmaf(af[i], bf[j], acc[i][j]);
    }
  }

  float invv[4], shf[4];
#pragma unroll
  for (int j = 0; j < 4; j++) {
    int n = n0 + tn0 + j;
    float iv = gamma[n] * rsqrtf(var[n] + 1e-5f);
    invv[j] = iv;
    shf[j] = beta[n] - mean[n] * iv;
  }
#pragma unroll
  for (int i = 0; i < 4; i++) {
    int m = m0 + tm0 + i;
    float4 o;
    o.x = fmaxf(acc[i][0] * invv[0] + shf[0], 0.f);
    o.y = fmaxf(acc[i][1] * invv[1] + shf[1], 0.f);
    o.z = fmaxf(acc[i][2] * invv[2] + shf[2], 0.f);
    o.w = fmaxf(acc[i][3] * invv[3] + shf[3], 0.f);
    *(float4*)&seq[(size_t)m * DM + n0 + tn0] = o;
  }
}

// ---------------- generic fp32 GEMM: C[M][N] = A[M][K] * Bw[N][K]^T ----------------
template <int BM, int BN, int BK, int TM, int TN>
__global__ __launch_bounds__(256) void k_gemm(
    const float* __restrict__ A, const float* __restrict__ Bw,
    float* __restrict__ C, int M, int N, int K) {
  static_assert((BM / TM) * (BN / TN) == 256, "256 threads");
  __shared__ float As[BK][BM + 4];
  __shared__ float Bs[BK][BN + 4];

  const int tid = threadIdx.x;
  const int tx = tid % (BN / TN);
  const int ty = tid / (BN / TN);
  const int tn0 = tx * TN;
  const int tm0 = ty * TM;
  const int n0 = blockIdx.x * BN;
  const int m0 = blockIdx.y * BM;
  const int KQ = BK / 4;

  float acc[TM][TN];
#pragma unroll
  for (int i = 0; i < TM; i++)
#pragma unroll
    for (int j = 0; j < TN; j++) acc[i][j] = 0.f;

  for (int k0 = 0; k0 < K; k0 += BK) {
    __syncthreads();
    for (int e = tid; e < BM * KQ; e += 256) {
      int row = e / KQ, kq = e - row * KQ;
      float4 q = *(const float4*)&A[(size_t)(m0 + row) * K + k0 + kq * 4];
      As[kq * 4 + 0][row] = q.x; As[kq * 4 + 1][row] = q.y;
      As[kq * 4 + 2][row] = q.z; As[kq * 4 + 3][row] = q.w;
    }
    for (int e = tid; e < BN * KQ; e += 256) {
      int row = e / KQ, kq = e - row * KQ;
      float4 q = *(const float4*)&Bw[(size_t)(n0 + row) * K + k0 + kq * 4];
      Bs[kq * 4 + 0][row] = q.x; Bs[kq * 4 + 1][row] = q.y;
      Bs[kq * 4 + 2][row] = q.z; Bs[kq * 4 + 3][row] = q.w;
    }
    __syncthreads();

#pragma unroll
    for (int kk = 0; kk < BK; kk++) {
      float af[TM], bf[TN];
      if constexpr (TM % 4 == 0) {
#pragma unroll
        for (int i = 0; i < TM / 4; i++) {
          float4 q = *(const float4*)&As[kk][tm0 + 4 * i];
          af[4 * i] = q.x; af[4 * i + 1] = q.y; af[4 * i + 2] = q.z; af[4 * i + 3] = q.w;
        }
      } else {
#pragma unroll
        for (int i = 0; i < TM; i++) af[i] = As[kk][tm0 + i];
      }
      if constexpr (TN % 4 == 0) {
#pragma unroll
        for (int j = 0; j < TN / 4; j++) {
          float4 q = *(const float4*)&Bs[kk][tn0 + 4 * j];
          bf[4 * j] = q.x; bf[4 * j + 1] = q.y; bf[4 * j + 2] = q.z; bf[4 * j + 3] = q.w;
        }
      } else {
#pragma unroll
        for (int j = 0; j < TN; j++) bf[j] = Bs[kk][tn0 + j];
      }
#pragma unroll
      for (int i = 0; i < TM; i++)
#pragma unroll
        for (int j = 0; j < TN; j++) acc[i][j] = fmaf(af[i], bf[j], acc[i][j]);
    }
  }

#pragma unroll
  for (int i = 0; i < TM; i++) {
    float* cp = &C[(size_t)(m0 + tm0 + i) * N + n0 + tn0];
    if constexpr (TN % 4 == 0) {
#pragma unroll
      for (int j = 0; j < TN; j += 4) {
        float4 q = {acc[i][j], acc[i][j + 1], acc[i][j + 2], acc[i][j + 3]};
        *(float4*)(cp + j) = q;
      }
    } else {
#pragma unroll
      for (int j = 0; j < TN; j++) cp[j] = acc[i][j];
    }
  }
}

// ---------------- causal depthwise conv1d (k=4) + bias + SiLU ----------------
__global__ __launch_bounds__(256) void k_dwconv(
    const float* __restrict__ xz, const float* __restrict__ w1,
    const float* __restrict__ b1, float* __restrict__ uAct) {
  int l = blockIdx.x;
  int b = blockIdx.y;
  int d = threadIdx.x;
#pragma unroll
  for (int half = 0; half < 2; half++, d += 256) {
    float4 wq = *(const float4*)&w1[d * 4];
    float acc = b1[d];
    if (l >= 3) acc = fmaf(xz[((size_t)(b * L_SEQ + l - 3)) * 1024 + d], wq.x, acc);
    if (l >= 2) acc = fmaf(xz[((size_t)(b * L_SEQ + l - 2)) * 1024 + d], wq.y, acc);
    if (l >= 1) acc = fmaf(xz[((size_t)(b * L_SEQ + l - 1)) * 1024 + d], wq.z, acc);
    acc = fmaf(xz[((size_t)(b * L_SEQ + l)) * 1024 + d], wq.w, acc);
    float sil = acc / (1.f + __expf(-acc));
    uAct[((size_t)(b * L_SEQ + l)) * DI + d] = sil;
  }
}

// ---------------- dt_proj + softplus -> delta [B*L][512] ----------------
__global__ __launch_bounds__(256) void k_dtproj(
    const float* __restrict__ x_dbl, const float* __restrict__ dtw,
    const float* __restrict__ dtb, float* __restrict__ delta) {
  __shared__ float xs[8][16];
  int m0 = blockIdx.x * 8;
  int tid = threadIdx.x;
  if (tid < 128) {
    int r = tid >> 4, k = tid & 15;
    xs[r][k] = x_dbl[(size_t)(m0 + r) * XPN + k];
  }
  __syncthreads();
  int n = tid;
#pragma unroll
  for (int half = 0; half < 2; half++, n += 256) {
    float4 w0 = *(const float4*)&dtw[n * 16];
    float4 w1 = *(const float4*)&dtw[n * 16 + 4];
    float4 w2 = *(const float4*)&dtw[n * 16 + 8];
    float4 w3 = *(const float4*)&dtw[n * 16 + 12];
    float bias = dtb[n];
#pragma unroll
    for (int r = 0; r < 8; r++) {
      float4 x0 = *(const float4*)&xs[r][0];
      float4 x1 = *(const float4*)&xs[r][4];
      float4 x2 = *(const float4*)&xs[r][8];
      float4 x3 = *(const float4*)&xs[r][12];
      float s = bias;
      s = fmaf(w0.x, x0.x, s); s = fmaf(w0.y, x0.y, s); s = fmaf(w0.z, x0.z, s); s = fmaf(w0.w, x0.w, s);
      s = fmaf(w1.x, x1.x, s); s = fmaf(w1.y, x1.y, s); s = fmaf(w1.z, x1.z, s); s = fmaf(w1.w, x1.w, s);
      s = fmaf(w2.x, x2.x, s); s = fmaf(w2.y, x2.y, s); s = fmaf(w2.z, x2.z, s); s = fmaf(w2.w, x2.w, s);
      s = fmaf(w3.x, x3.x, s); s = fmaf(w3.y, x3.y, s); s = fmaf(w3.z, x3.z, s); s = fmaf(w3.w, x3.w, s);
      float sp = fmaxf(s, 0.f) + log1pf(expf(-fabsf(s)));
      delta[(size_t)(m0 + r) * DI + n] = sp;
    }
  }
}

// ---------------- selective scan, 3-phase chunked ----------------
__global__ __launch_bounds__(256) void k_scan1(
    const float* __restrict__ delta, const float* __restrict__ uA,
    const float* __restrict__ x_dbl, const float* __restrict__ A_log,
    float* __restrict__ Sbuf, float* __restrict__ Sumx) {
  int d = blockIdx.x * 256 + threadIdx.x;
  int b = blockIdx.y;
  int c = blockIdx.z;

  float a[DSTATE];
#pragma unroll
  for (int q = 0; q < 8; q++) {
    float4 av = *(const float4*)&A_log[d * DSTATE + 4 * q];
    a[4 * q + 0] = -__expf(av.x); a[4 * q + 1] = -__expf(av.y);
    a[4 * q + 2] = -__expf(av.z); a[4 * q + 3] = -__expf(av.w);
  }
  float s[DSTATE];
#pragma unroll
  for (int n = 0; n < DSTATE; n++) s[n] = 0.f;
  float sumx = 0.f;

  int t0 = c * CHLEN;
  const float* dp = delta + ((size_t)(b * L_SEQ + t0)) * DI + d;
  const float* up = uA + ((size_t)(b * L_SEQ + t0)) * DI + d;
  const float* bp = x_dbl + ((size_t)(b * L_SEQ + t0)) * XPN + 16;

#pragma unroll 4
  for (int t = 0; t < CHLEN; t++) {
    float xw = *dp; float uu = *up;
    float4 Bq[8];
#pragma unroll
    for (int q = 0; q < 8; q++) Bq[q] = *(const float4*)(bp + 4 * q);
    dp += DI; up += DI; bp += XPN;
    float du = xw * uu;
    sumx += xw;
#pragma unroll
    for (int q = 0; q < 8; q++) {
      s[4 * q + 0] = fmaf(s[4 * q + 0], __expf(xw * a[4 * q + 0]), du * Bq[q].x);
      s[4 * q + 1] = fmaf(s[4 * q + 1], __expf(xw * a[4 * q + 1]), du * Bq[q].y);
      s[4 * q + 2] = fmaf(s[4 * q + 2], __expf(xw * a[4 * q + 2]), du * Bq[q].z);
      s[4 * q + 3] = fmaf(s[4 * q + 3], __expf(xw * a[4 * q + 3]), du * Bq[q].w);
    }
  }

  float* sb = Sbuf + ((size_t)c * 65536) + ((size_t)(b * DI + d)) * DSTATE;
#pragma unroll
  for (int q = 0; q < 8; q++) {
    float4 v = {s[4 * q], s[4 * q + 1], s[4 * q + 2], s[4 * q + 3]};
    *(float4*)(sb + 4 * q) = v;
  }
  Sumx[c * (NB * DI) + b * DI + d] = sumx;
}

__global__ __launch_bounds__(256) void k_scan2(float* __restrict__ Sbuf,
                                               const float* __restrict__ Sumx,
                                               const float* __restrict__ A_log) {
  int gidx = blockIdx.x * 256 + threadIdx.x;   // (b*DI+d)*32+n
  int bd = gidx >> 5;
  int d = bd & (DI - 1);
  int n = gidx & 31;
  float a = -__expf(A_log[d * DSTATE + n]);
  float carry = 0.f;
  for (int c = 0; c < NCHUNK; c++) {
    float s = Sbuf[(size_t)c * 65536 + gidx];
    float p = __expf(a * Sumx[c * (NB * DI) + bd]);
    Sbuf[(size_t)c * 65536 + gidx] = carry;
    carry = fmaf(p, carry, s);
  }
}

__global__ __launch_bounds__(256) void k_scan3(
    const float* __restrict__ delta, const float* __restrict__ uA,
    const float* __restrict__ x_dbl, const float* __restrict__ A_log,
    const float* __restrict__ Sbuf, const float* __restrict__ xz,
    const float* __restrict__ Dv, float* __restrict__ y) {
  int d = blockIdx.x * 256 + threadIdx.x;
  int b = blockIdx.y;
  int c = blockIdx.z;

  float a[DSTATE];
#pragma unroll
  for (int q = 0; q < 8; q++) {
    float4 av = *(const float4*)&A_log[d * DSTATE + 4 * q];
    a[4 * q + 0] = -__expf(av.x); a[4 * q + 1] = -__expf(av.y);
    a[4 * q + 2] = -__expf(av.z); a[4 * q + 3] = -__expf(av.w);
  }
  float s[DSTATE];
  const float* sb = Sbuf + ((size_t)c * 65536) + ((size_t)(b * DI + d)) * DSTATE;
#pragma unroll
  for (int q = 0; q < 8; q++) {
    float4 v = *(const float4*)(sb + 4 * q);
    s[4 * q] = v.x; s[4 * q + 1] = v.y; s[4 * q + 2] = v.z; s[4 * q + 3] = v.w;
  }
  float Dd = Dv[d];

  int t0 = c * CHLEN;
  const float* dp = delta + ((size_t)(b * L_SEQ + t0)) * DI + d;
  const float* up = uA + ((size_t)(b * L_SEQ + t0)) * DI + d;
  const float* bp = x_dbl + ((size_t)(b * L_SEQ + t0)) * XPN + 16;
  const float* cp = x_dbl + ((size_t)(b * L_SEQ + t0)) * XPN + 48;
  const float* zp = xz + ((size_t)(b * L_SEQ + t0)) * 1024 + 512 + d;
  float* yp = y + ((size_t)(b * L_SEQ + t0)) * DI + d;

#pragma unroll 4
  for (int t = 0; t < CHLEN; t++) {
    float xw = *dp; float uu = *up; float zv = *zp;
    float4 Bq[8], Cq[8];
#pragma unroll
    for (int q = 0; q < 8; q++) Bq[q] = *(const float4*)(bp + 4 * q);
#pragma unroll
    for (int q = 0; q < 8; q++) Cq[q] = *(const float4*)(cp + 4 * q);
    dp += DI; up += DI; bp += XPN; cp += XPN; zp += 1024;
    float du = xw * uu;
    float yv = 0.f;
#pragma unroll
    for (int q = 0; q < 8; q++) {
      s[4 * q + 0] = fmaf(s[4 * q + 0], __expf(xw * a[4 * q + 0]), du * Bq[q].x);
      s[4 * q + 1] = fmaf(s[4 * q + 1], __expf(xw * a[4 * q + 1]), du * Bq[q].y);
      s[4 * q + 2] = fmaf(s[4 * q + 2], __expf(xw * a[4 * q + 2]), du * Bq[q].z);
      s[4 * q + 3] = fmaf(s[4 * q + 3], __expf(xw * a[4 * q + 3]), du * Bq[q].w);
      yv = fmaf(s[4 * q + 0], Cq[q].x, yv);
      yv = fmaf(s[4 * q + 1], Cq[q].y, yv);
      yv = fmaf(s[4 * q + 2], Cq[q].z, yv);
      yv = fmaf(s[4 * q + 3], Cq[q].w, yv);
    }
    float out = (yv + uu * Dd) * (zv / (1.f + __expf(-zv)));
    *yp = out;
    yp += DI;
  }
}

// ---------------- final transpose: [B][L][256] -> [B][256][L] ----------------
__global__ __launch_bounds__(256) void k_transpose_out(const float* __restrict__ src,
                                                       float* __restrict__ dst) {
  __shared__ float tile[32][33];
  int l0 = blockIdx.x * 32;
  int n0 = blockIdx.y * 32;
  int b = blockIdx.z;
  int tx = threadIdx.x & 31;
  int ty = threadIdx.x >> 5;   // 0..7
#pragma unroll
  for (int r = ty; r < 32; r += 8)
    tile[r][tx] = src[((size_t)(b * L_SEQ + l0 + r)) * DM + n0 + tx];
  __syncthreads();
#pragma unroll
  for (int r = ty; r < 32; r += 8)
    dst[((size_t)(b * DM + n0 + r)) * L_SEQ + l0 + tx] = tile[tx][r];
}

// ---------------- launcher ----------------
extern "C" void kernel_launch(void* const* d_in, const int* in_sizes, int n_in,
                              void* d_out, int out_size, void* d_ws, size_t ws_size,
                              hipStream_t stream) {
  const float* x     = (const float*)d_in[0];
  const float* cw    = (const float*)d_in[1];
  const float* gamma = (const float*)d_in[2];
  const float* beta  = (const float*)d_in[3];
  const float* mean  = (const float*)d_in[4];
  const float* var   = (const float*)d_in[5];
  const float* ipw   = (const float*)d_in[6];
  const float* c1w   = (const float*)d_in[7];
  const float* c1b   = (const float*)d_in[8];
  const float* xpw   = (const float*)d_in[9];
  const float* dtw   = (const float*)d_in[10];
  const float* dtb   = (const float*)d_in[11];
  const float* Alog  = (const float*)d_in[12];
  const float* Dv    = (const float*)d_in[13];
  const float* opw   = (const float*)d_in[14];
  float* out = (float*)d_out;

  float* ws = (float*)d_ws;
  size_t o = 0;
  float* seq   = ws + o; o += (size_t)NB * L_SEQ * DM;        // also GEMM-out scratch
  float* xz    = ws + o; o += (size_t)NB * L_SEQ * 1024;
  float* uAct  = ws + o; o += (size_t)NB * L_SEQ * DI;
  float* x_dbl = ws + o; o += (size_t)NB * L_SEQ * XPN;
  float* delta = ws + o; o += (size_t)NB * L_SEQ * DI;
  float* ybuf  = ws + o; o += (size_t)NB * L_SEQ * DI;
  float* xT    = ws + o; o += (size_t)NB * L_SEQ * D_IN;
  float* wT    = ws + o; o += (size_t)DM * 9 * D_IN;
  float* Sbuf  = ws + o; o += (size_t)NCHUNK * 65536;
  float* Sumx  = ws + o; o += (size_t)NCHUNK * NB * DI;

  k_transpose_x<<<2304, 256, 0, stream>>>(x, xT);
  k_transpose_w<<<576, 256, 0, stream>>>(cw, wT);
  k_convgemm<<<dim3(4, 144), 256, 0, stream>>>(xT, wT, gamma, beta, mean, var, seq);
  k_gemm<128, 128, 32, 8, 8><<<dim3(8, 72), 256, 0, stream>>>(seq, ipw, xz, 9216, 1024, 256);
  k_dwconv<<<dim3(2304, 4), 256, 0, stream>>>(xz, c1w, c1b, uAct);
  k_gemm<64, 80, 32, 4, 5><<<dim3(1, 144), 256, 0, stream>>>(uAct, xpw, x_dbl, 9216, 80, 512);
  k_dtproj<<<1152, 256, 0, stream>>>(x_dbl, dtw, dtb, delta);
  k_scan1<<<dim3(2, 4, NCHUNK), 256, 0, stream>>>(delta, uAct, x_dbl, Alog, Sbuf, Sumx);
  k_scan2<<<256, 256, 0, stream>>>(Sbuf, Sumx, Alog);
  k_scan3<<<dim3(2, 4, NCHUNK), 256, 0, stream>>>(delta, uAct, x_dbl, Alog, Sbuf, xz, Dv, ybuf);
  k_gemm<64, 128, 32, 4, 8><<<dim3(2, 144), 256, 0, stream>>>(ybuf, opw, seq, 9216, 256, 512);
  k_transpose_out<<<dim3(72, 8, 4), 256, 0, stream>>>(seq, out);
}

// Round 4
// 346.435 us; speedup vs baseline: 2.1559x; 1.4772x over previous
//
#include <hip/hip_runtime.h>
#include <hip/hip_bf16.h>
#include <cmath>

#define L_SEQ 2304
#define NB 4
#define D_IN 64
#define DM 256
#define DI 512
#define DSTATE 32
#define XPN 80
#define NCHUNK 64
#define CHLEN 36   // L_SEQ / NCHUNK

typedef unsigned short u16;
typedef __attribute__((ext_vector_type(8))) short bf16x8;
typedef __attribute__((ext_vector_type(4))) float f32x4;

__device__ __forceinline__ u16 f2b(float f) {
  __hip_bfloat16 h = __float2bfloat16(f);
  return *(u16*)&h;
}

// ---------------- prep ----------------
// x [4][64][48][48] -> xT [4][48*48][64] fp32
__global__ __launch_bounds__(256) void k_transpose_x(const float* __restrict__ x,
                                                     float* __restrict__ xT) {
  int id = blockIdx.x * 256 + threadIdx.x;   // 589824
  int ic = id & 63;
  int sp = id >> 6;
  int b = sp / L_SEQ, pos = sp - b * L_SEQ;
  xT[id] = x[(size_t)(b * D_IN + ic) * L_SEQ + pos];
}

// conv_w [256][64][3][3] -> wTb bf16 [256][576] (k = tap*64+ic)
__global__ __launch_bounds__(256) void k_transpose_w(const float* __restrict__ w,
                                                     u16* __restrict__ wTb) {
  int id = blockIdx.x * 256 + threadIdx.x;   // 147456
  int ic = id & 63;
  int rest = id >> 6;
  int oc = rest / 9, tap = rest - oc * 9;
  wTb[id] = f2b(w[(size_t)(oc * D_IN + ic) * 9 + tap]);
}

// generic fp32 -> bf16 cast
__global__ __launch_bounds__(256) void k_cast(const float* __restrict__ s,
                                              u16* __restrict__ d, int n) {
  int id = blockIdx.x * 256 + threadIdx.x;
  if (id < n) d[id] = f2b(s[id]);
}

// im2col: xT fp32 -> im [9216][576] bf16, zero-filled borders
__global__ __launch_bounds__(256) void k_im2col(const float* __restrict__ xT,
                                                u16* __restrict__ im) {
  int id = blockIdx.x * 256 + threadIdx.x;   // 9216*72 = 663552
  int m = id / 72;
  int g8 = id - m * 72;
  int tap = g8 >> 3;
  int ic0 = (g8 & 7) * 8;
  int b = m / L_SEQ; int rem = m - b * L_SEQ;
  int y = rem / 48;  int xx = rem - y * 48;
  int yy = y + tap / 3 - 1, ww = xx + tap % 3 - 1;
  alignas(16) u16 o[8];
  if ((unsigned)yy < 48u && (unsigned)ww < 48u) {
    const float* p = &xT[(((size_t)(b * 48 + yy)) * 48 + ww) * 64 + ic0];
    float4 q0 = *(const float4*)p;
    float4 q1 = *(const float4*)(p + 4);
    o[0] = f2b(q0.x); o[1] = f2b(q0.y); o[2] = f2b(q0.z); o[3] = f2b(q0.w);
    o[4] = f2b(q1.x); o[5] = f2b(q1.y); o[6] = f2b(q1.z); o[7] = f2b(q1.w);
  } else {
#pragma unroll
    for (int i = 0; i < 8; i++) o[i] = 0;
  }
  *(uint4*)&im[(size_t)m * 576 + g8 * 8] = *(uint4*)o;
}

// ---------------- bf16 MFMA GEMM: C[M][N] = A[M][K] * Bw[N][K]^T ----------------
// A, Bw bf16 k-major. EPI 0: fp32 out. EPI 1: BN+ReLU, bf16 out.
// 256 threads = 4 waves arranged (BM/WM) x (BN/WN). BK=32.
template <int BM, int BN, int WM, int WN, int EPI>
__global__ __launch_bounds__(256) void k_mgemm(
    const u16* __restrict__ A, const u16* __restrict__ Bw,
    float* __restrict__ Cf, u16* __restrict__ Cb,
    const float* __restrict__ g, const float* __restrict__ be,
    const float* __restrict__ mu, const float* __restrict__ va,
    int M, int N, int K) {
  constexpr int BK = 32;
  constexpr int LDR = BK + 8;            // 40 ushorts = 80 B rows (bank-friendly, 16B aligned)
  __shared__ u16 As[BM * LDR];
  __shared__ u16 Bs[BN * LDR];
  const int tid = threadIdx.x;
  const int lane = tid & 63;
  const int wid = tid >> 6;
  constexpr int NWN = BN / WN;
  const int wn = (wid % NWN) * WN;
  const int wm = (wid / NWN) * WM;
  const int ln15 = lane & 15;
  const int quad = lane >> 4;
  const int n0 = blockIdx.x * BN;
  const int m0 = blockIdx.y * BM;
  constexpr int TMN = WM / 16, TNN = WN / 16;

  f32x4 acc[TMN][TNN];
#pragma unroll
  for (int i = 0; i < TMN; i++)
#pragma unroll
    for (int j = 0; j < TNN; j++) acc[i][j] = (f32x4){0.f, 0.f, 0.f, 0.f};

  const int srow = tid >> 2;             // 0..63
  const int spart = (tid & 3) * 8;       // k offset in ushorts (16B chunks)

  for (int k0 = 0; k0 < K; k0 += BK) {
    __syncthreads();
#pragma unroll
    for (int p = 0; p < BM / 64; p++) {
      int row = srow + p * 64;
      uint4 q = *(const uint4*)&A[(size_t)(m0 + row) * K + k0 + spart];
      *(uint4*)&As[row * LDR + spart] = q;
    }
#pragma unroll
    for (int p = 0; p < BN / 64; p++) {
      int row = srow + p * 64;
      uint4 q = *(const uint4*)&Bw[(size_t)(n0 + row) * K + k0 + spart];
      *(uint4*)&Bs[row * LDR + spart] = q;
    }
    __syncthreads();

    bf16x8 af[TMN], bfr[TNN];
#pragma unroll
    for (int i = 0; i < TMN; i++)
      af[i] = *(const bf16x8*)&As[(wm + i * 16 + ln15) * LDR + quad * 8];
#pragma unroll
    for (int j = 0; j < TNN; j++)
      bfr[j] = *(const bf16x8*)&Bs[(wn + j * 16 + ln15) * LDR + quad * 8];
#pragma unroll
    for (int i = 0; i < TMN; i++)
#pragma unroll
      for (int j = 0; j < TNN; j++)
        acc[i][j] = __builtin_amdgcn_mfma_f32_16x16x32_bf16(af[i], bfr[j], acc[i][j], 0, 0, 0);
  }

  if constexpr (EPI == 0) {
#pragma unroll
    for (int i = 0; i < TMN; i++) {
      int mb = m0 + wm + i * 16 + quad * 4;
#pragma unroll
      for (int j = 0; j < TNN; j++) {
        int n = n0 + wn + j * 16 + ln15;
#pragma unroll
        for (int r = 0; r < 4; r++)
          Cf[(size_t)(mb + r) * N + n] = acc[i][j][r];
      }
    }
  } else {
#pragma unroll
    for (int j = 0; j < TNN; j++) {
      int n = n0 + wn + j * 16 + ln15;
      float iv = g[n] * rsqrtf(va[n] + 1e-5f);
      float sh = be[n] - mu[n] * iv;
#pragma unroll
      for (int i = 0; i < TMN; i++) {
        int mb = m0 + wm + i * 16 + quad * 4;
#pragma unroll
        for (int r = 0; r < 4; r++) {
          float v = fmaxf(acc[i][j][r] * iv + sh, 0.f);
          Cb[(size_t)(mb + r) * N + n] = f2b(v);
        }
      }
    }
  }
}

// ---------------- generic fp32 GEMM (kept for x_proj only) ----------------
template <int BM, int BN, int BK, int TM, int TN>
__global__ __launch_bounds__(256) void k_gemm(
    const float* __restrict__ A, const float* __restrict__ Bw,
    float* __restrict__ C, int M, int N, int K) {
  static_assert((BM / TM) * (BN / TN) == 256, "256 threads");
  __shared__ float As[BK][BM + 4];
  __shared__ float Bs[BK][BN + 4];
  const int tid = threadIdx.x;
  const int tx = tid % (BN / TN);
  const int ty = tid / (BN / TN);
  const int tn0 = tx * TN;
  const int tm0 = ty * TM;
  const int n0 = blockIdx.x * BN;
  const int m0 = blockIdx.y * BM;
  const int KQ = BK / 4;

  float acc[TM][TN];
#pragma unroll
  for (int i = 0; i < TM; i++)
#pragma unroll
    for (int j = 0; j < TN; j++) acc[i][j] = 0.f;

  for (int k0 = 0; k0 < K; k0 += BK) {
    __syncthreads();
    for (int e = tid; e < BM * KQ; e += 256) {
      int row = e / KQ, kq = e - row * KQ;
      float4 q = *(const float4*)&A[(size_t)(m0 + row) * K + k0 + kq * 4];
      As[kq * 4 + 0][row] = q.x; As[kq * 4 + 1][row] = q.y;
      As[kq * 4 + 2][row] = q.z; As[kq * 4 + 3][row] = q.w;
    }
    for (int e = tid; e < BN * KQ; e += 256) {
      int row = e / KQ, kq = e - row * KQ;
      float4 q = *(const float4*)&Bw[(size_t)(n0 + row) * K + k0 + kq * 4];
      Bs[kq * 4 + 0][row] = q.x; Bs[kq * 4 + 1][row] = q.y;
      Bs[kq * 4 + 2][row] = q.z; Bs[kq * 4 + 3][row] = q.w;
    }
    __syncthreads();

#pragma unroll
    for (int kk = 0; kk < BK; kk++) {
      float af[TM], bf[TN];
      if constexpr (TM % 4 == 0) {
#pragma unroll
        for (int i = 0; i < TM / 4; i++) {
          float4 q = *(const float4*)&As[kk][tm0 + 4 * i];
          af[4 * i] = q.x; af[4 * i + 1] = q.y; af[4 * i + 2] = q.z; af[4 * i + 3] = q.w;
        }
      } else {
#pragma unroll
        for (int i = 0; i < TM; i++) af[i] = As[kk][tm0 + i];
      }
      if constexpr (TN % 4 == 0) {
#pragma unroll
        for (int j = 0; j < TN / 4; j++) {
          float4 q = *(const float4*)&Bs[kk][tn0 + 4 * j];
          bf[4 * j] = q.x; bf[4 * j + 1] = q.y; bf[4 * j + 2] = q.z; bf[4 * j + 3] = q.w;
        }
      } else {
#pragma unroll
        for (int j = 0; j < TN; j++) bf[j] = Bs[kk][tn0 + j];
      }
#pragma unroll
      for (int i = 0; i < TM; i++)
#pragma unroll
        for (int j = 0; j < TN; j++) acc[i][j] = fmaf(af[i], bf[j], acc[i][j]);
    }
  }

#pragma unroll
  for (int i = 0; i < TM; i++) {
    float* cp = &C[(size_t)(m0 + tm0 + i) * N + n0 + tn0];
    if constexpr (TN % 4 == 0) {
#pragma unroll
      for (int j = 0; j < TN; j += 4) {
        float4 q = {acc[i][j], acc[i][j + 1], acc[i][j + 2], acc[i][j + 3]};
        *(float4*)(cp + j) = q;
      }
    } else {
#pragma unroll
      for (int j = 0; j < TN; j++) cp[j] = acc[i][j];
    }
  }
}

// ---------------- causal depthwise conv1d (k=4) + bias + SiLU ----------------
__global__ __launch_bounds__(256) void k_dwconv(
    const float* __restrict__ xz, const float* __restrict__ w1,
    const float* __restrict__ b1, float* __restrict__ uAct) {
  int l = blockIdx.x;
  int b = blockIdx.y;
  int d = threadIdx.x;
#pragma unroll
  for (int half = 0; half < 2; half++, d += 256) {
    float4 wq = *(const float4*)&w1[d * 4];
    float acc = b1[d];
    if (l >= 3) acc = fmaf(xz[((size_t)(b * L_SEQ + l - 3)) * 1024 + d], wq.x, acc);
    if (l >= 2) acc = fmaf(xz[((size_t)(b * L_SEQ + l - 2)) * 1024 + d], wq.y, acc);
    if (l >= 1) acc = fmaf(xz[((size_t)(b * L_SEQ + l - 1)) * 1024 + d], wq.z, acc);
    acc = fmaf(xz[((size_t)(b * L_SEQ + l)) * 1024 + d], wq.w, acc);
    float sil = acc / (1.f + __expf(-acc));
    uAct[((size_t)(b * L_SEQ + l)) * DI + d] = sil;
  }
}

// ---------------- dt_proj + softplus -> delta [B*L][512] ----------------
__global__ __launch_bounds__(256) void k_dtproj(
    const float* __restrict__ x_dbl, const float* __restrict__ dtw,
    const float* __restrict__ dtb, float* __restrict__ delta) {
  __shared__ float xs[8][16];
  int m0 = blockIdx.x * 8;
  int tid = threadIdx.x;
  if (tid < 128) {
    int r = tid >> 4, k = tid & 15;
    xs[r][k] = x_dbl[(size_t)(m0 + r) * XPN + k];
  }
  __syncthreads();
  int n = tid;
#pragma unroll
  for (int half = 0; half < 2; half++, n += 256) {
    float4 w0 = *(const float4*)&dtw[n * 16];
    float4 w1 = *(const float4*)&dtw[n * 16 + 4];
    float4 w2 = *(const float4*)&dtw[n * 16 + 8];
    float4 w3 = *(const float4*)&dtw[n * 16 + 12];
    float bias = dtb[n];
#pragma unroll
    for (int r = 0; r < 8; r++) {
      float4 x0 = *(const float4*)&xs[r][0];
      float4 x1 = *(const float4*)&xs[r][4];
      float4 x2 = *(const float4*)&xs[r][8];
      float4 x3 = *(const float4*)&xs[r][12];
      float s = bias;
      s = fmaf(w0.x, x0.x, s); s = fmaf(w0.y, x0.y, s); s = fmaf(w0.z, x0.z, s); s = fmaf(w0.w, x0.w, s);
      s = fmaf(w1.x, x1.x, s); s = fmaf(w1.y, x1.y, s); s = fmaf(w1.z, x1.z, s); s = fmaf(w1.w, x1.w, s);
      s = fmaf(w2.x, x2.x, s); s = fmaf(w2.y, x2.y, s); s = fmaf(w2.z, x2.z, s); s = fmaf(w2.w, x2.w, s);
      s = fmaf(w3.x, x3.x, s); s = fmaf(w3.y, x3.y, s); s = fmaf(w3.z, x3.z, s); s = fmaf(w3.w, x3.w, s);
      float sp = fmaxf(s, 0.f) + log1pf(expf(-fabsf(s)));
      delta[(size_t)(m0 + r) * DI + n] = sp;
    }
  }
}

// ---------------- selective scan, 3-phase chunked ----------------
__global__ __launch_bounds__(256) void k_scan1(
    const float* __restrict__ delta, const float* __restrict__ uA,
    const float* __restrict__ x_dbl, const float* __restrict__ A_log,
    float* __restrict__ Sbuf, float* __restrict__ Sumx) {
  int d = blockIdx.x * 256 + threadIdx.x;
  int b = blockIdx.y;
  int c = blockIdx.z;

  float a[DSTATE];
#pragma unroll
  for (int q = 0; q < 8; q++) {
    float4 av = *(const float4*)&A_log[d * DSTATE + 4 * q];
    a[4 * q + 0] = -__expf(av.x); a[4 * q + 1] = -__expf(av.y);
    a[4 * q + 2] = -__expf(av.z); a[4 * q + 3] = -__expf(av.w);
  }
  float s[DSTATE];
#pragma unroll
  for (int n = 0; n < DSTATE; n++) s[n] = 0.f;
  float sumx = 0.f;

  int t0 = c * CHLEN;
  const float* dp = delta + ((size_t)(b * L_SEQ + t0)) * DI + d;
  const float* up = uA + ((size_t)(b * L_SEQ + t0)) * DI + d;
  const float* bp = x_dbl + ((size_t)(b * L_SEQ + t0)) * XPN + 16;

#pragma unroll 4
  for (int t = 0; t < CHLEN; t++) {
    float xw = *dp; float uu = *up;
    float4 Bq[8];
#pragma unroll
    for (int q = 0; q < 8; q++) Bq[q] = *(const float4*)(bp + 4 * q);
    dp += DI; up += DI; bp += XPN;
    float du = xw * uu;
    sumx += xw;
#pragma unroll
    for (int q = 0; q < 8; q++) {
      s[4 * q + 0] = fmaf(s[4 * q + 0], __expf(xw * a[4 * q + 0]), du * Bq[q].x);
      s[4 * q + 1] = fmaf(s[4 * q + 1], __expf(xw * a[4 * q + 1]), du * Bq[q].y);
      s[4 * q + 2] = fmaf(s[4 * q + 2], __expf(xw * a[4 * q + 2]), du * Bq[q].z);
      s[4 * q + 3] = fmaf(s[4 * q + 3], __expf(xw * a[4 * q + 3]), du * Bq[q].w);
    }
  }

  float* sb = Sbuf + ((size_t)c * 65536) + ((size_t)(b * DI + d)) * DSTATE;
#pragma unroll
  for (int q = 0; q < 8; q++) {
    float4 v = {s[4 * q], s[4 * q + 1], s[4 * q + 2], s[4 * q + 3]};
    *(float4*)(sb + 4 * q) = v;
  }
  Sumx[c * (NB * DI) + b * DI + d] = sumx;
}

__global__ __launch_bounds__(256) void k_scan2(float* __restrict__ Sbuf,
                                               const float* __restrict__ Sumx,
                                               const float* __restrict__ A_log) {
  int gidx = blockIdx.x * 256 + threadIdx.x;   // (b*DI+d)*32+n
  int bd = gidx >> 5;
  int d = bd & (DI - 1);
  int n = gidx & 31;
  float a = -__expf(A_log[d * DSTATE + n]);
  float carry = 0.f;
  for (int c = 0; c < NCHUNK; c++) {
    float s = Sbuf[(size_t)c * 65536 + gidx];
    float p = __expf(a * Sumx[c * (NB * DI) + bd]);
    Sbuf[(size_t)c * 65536 + gidx] = carry;
    carry = fmaf(p, carry, s);
  }
}

__global__ __launch_bounds__(256) void k_scan3(
    const float* __restrict__ delta, const float* __restrict__ uA,
    const float* __restrict__ x_dbl, const float* __restrict__ A_log,
    const float* __restrict__ Sbuf, const float* __restrict__ xz,
    const float* __restrict__ Dv, u16* __restrict__ y) {
  int d = blockIdx.x * 256 + threadIdx.x;
  int b = blockIdx.y;
  int c = blockIdx.z;

  float a[DSTATE];
#pragma unroll
  for (int q = 0; q < 8; q++) {
    float4 av = *(const float4*)&A_log[d * DSTATE + 4 * q];
    a[4 * q + 0] = -__expf(av.x); a[4 * q + 1] = -__expf(av.y);
    a[4 * q + 2] = -__expf(av.z); a[4 * q + 3] = -__expf(av.w);
  }
  float s[DSTATE];
  const float* sb = Sbuf + ((size_t)c * 65536) + ((size_t)(b * DI + d)) * DSTATE;
#pragma unroll
  for (int q = 0; q < 8; q++) {
    float4 v = *(const float4*)(sb + 4 * q);
    s[4 * q] = v.x; s[4 * q + 1] = v.y; s[4 * q + 2] = v.z; s[4 * q + 3] = v.w;
  }
  float Dd = Dv[d];

  int t0 = c * CHLEN;
  const float* dp = delta + ((size_t)(b * L_SEQ + t0)) * DI + d;
  const float* up = uA + ((size_t)(b * L_SEQ + t0)) * DI + d;
  const float* bp = x_dbl + ((size_t)(b * L_SEQ + t0)) * XPN + 16;
  const float* cp = x_dbl + ((size_t)(b * L_SEQ + t0)) * XPN + 48;
  const float* zp = xz + ((size_t)(b * L_SEQ + t0)) * 1024 + 512 + d;
  u16* yp = y + ((size_t)(b * L_SEQ + t0)) * DI + d;

#pragma unroll 4
  for (int t = 0; t < CHLEN; t++) {
    float xw = *dp; float uu = *up; float zv = *zp;
    float4 Bq[8], Cq[8];
#pragma unroll
    for (int q = 0; q < 8; q++) Bq[q] = *(const float4*)(bp + 4 * q);
#pragma unroll
    for (int q = 0; q < 8; q++) Cq[q] = *(const float4*)(cp + 4 * q);
    dp += DI; up += DI; bp += XPN; cp += XPN; zp += 1024;
    float du = xw * uu;
    float yv = 0.f;
#pragma unroll
    for (int q = 0; q < 8; q++) {
      s[4 * q + 0] = fmaf(s[4 * q + 0], __expf(xw * a[4 * q + 0]), du * Bq[q].x);
      s[4 * q + 1] = fmaf(s[4 * q + 1], __expf(xw * a[4 * q + 1]), du * Bq[q].y);
      s[4 * q + 2] = fmaf(s[4 * q + 2], __expf(xw * a[4 * q + 2]), du * Bq[q].z);
      s[4 * q + 3] = fmaf(s[4 * q + 3], __expf(xw * a[4 * q + 3]), du * Bq[q].w);
      yv = fmaf(s[4 * q + 0], Cq[q].x, yv);
      yv = fmaf(s[4 * q + 1], Cq[q].y, yv);
      yv = fmaf(s[4 * q + 2], Cq[q].z, yv);
      yv = fmaf(s[4 * q + 3], Cq[q].w, yv);
    }
    float out = (yv + uu * Dd) * (zv / (1.f + __expf(-zv)));
    *yp = f2b(out);
    yp += DI;
  }
}

// ---------------- final transpose: [B][L][256] -> [B][256][L] ----------------
__global__ __launch_bounds__(256) void k_transpose_out(const float* __restrict__ src,
                                                       float* __restrict__ dst) {
  __shared__ float tile[32][33];
  int l0 = blockIdx.x * 32;
  int n0 = blockIdx.y * 32;
  int b = blockIdx.z;
  int tx = threadIdx.x & 31;
  int ty = threadIdx.x >> 5;
#pragma unroll
  for (int r = ty; r < 32; r += 8)
    tile[r][tx] = src[((size_t)(b * L_SEQ + l0 + r)) * DM + n0 + tx];
  __syncthreads();
#pragma unroll
  for (int r = ty; r < 32; r += 8)
    dst[((size_t)(b * DM + n0 + r)) * L_SEQ + l0 + tx] = tile[tx][r];
}

// ---------------- launcher ----------------
extern "C" void kernel_launch(void* const* d_in, const int* in_sizes, int n_in,
                              void* d_out, int out_size, void* d_ws, size_t ws_size,
                              hipStream_t stream) {
  const float* x     = (const float*)d_in[0];
  const float* cw    = (const float*)d_in[1];
  const float* gamma = (const float*)d_in[2];
  const float* beta  = (const float*)d_in[3];
  const float* mean  = (const float*)d_in[4];
  const float* var   = (const float*)d_in[5];
  const float* ipw   = (const float*)d_in[6];
  const float* c1w   = (const float*)d_in[7];
  const float* c1b   = (const float*)d_in[8];
  const float* xpw   = (const float*)d_in[9];
  const float* dtw   = (const float*)d_in[10];
  const float* dtb   = (const float*)d_in[11];
  const float* Alog  = (const float*)d_in[12];
  const float* Dv    = (const float*)d_in[13];
  const float* opw   = (const float*)d_in[14];
  float* out = (float*)d_out;

  float* ws = (float*)d_ws;
  size_t o = 0;
  u16*   ybufb = (u16*)(ws + o);   o += (size_t)NB * L_SEQ * DI / 2;   // bf16 [9216][512]
  float* xz    = ws + o;           o += (size_t)NB * L_SEQ * 1024;
  float* uAct  = ws + o;           o += (size_t)NB * L_SEQ * DI;
  float* x_dbl = ws + o;           o += (size_t)NB * L_SEQ * XPN;
  float* delta = ws + o;           o += (size_t)NB * L_SEQ * DI;       // also out_proj fp32 scratch
  float* xT    = ws + o;           o += (size_t)NB * L_SEQ * D_IN;
  float* Sbuf  = ws + o;           o += (size_t)NCHUNK * 65536;        // also im2col bf16 scratch
  float* Sumx  = ws + o;           o += (size_t)NCHUNK * NB * DI;
  u16*   seqb  = (u16*)(ws + o);   o += (size_t)NB * L_SEQ * DM / 2;   // bf16 [9216][256]
  u16*   wTb   = (u16*)(ws + o);   o += (size_t)DM * 9 * D_IN / 2;
  u16*   ipwb  = (u16*)(ws + o);   o += (size_t)2 * DI * DM / 2;
  u16*   opwb  = (u16*)(ws + o);   o += (size_t)DM * DI / 2;
  u16*   im2c  = (u16*)Sbuf;                                           // [9216][576] bf16
  float* osc   = delta;                                                // [9216][256] fp32

  k_transpose_x<<<2304, 256, 0, stream>>>(x, xT);
  k_transpose_w<<<576, 256, 0, stream>>>(cw, wTb);
  k_cast<<<1024, 256, 0, stream>>>(ipw, ipwb, 2 * DI * DM);
  k_cast<<<512, 256, 0, stream>>>(opw, opwb, DM * DI);
  k_im2col<<<2592, 256, 0, stream>>>(xT, im2c);
  // conv3x3+BN+ReLU: [9216][576] x [256][576]^T -> seqb bf16
  k_mgemm<64, 128, 32, 64, 1><<<dim3(2, 144), 256, 0, stream>>>(
      im2c, wTb, nullptr, seqb, gamma, beta, mean, var, 9216, 256, 576);
  // in_proj: [9216][256] x [1024][256]^T -> xz fp32
  k_mgemm<128, 128, 64, 64, 0><<<dim3(8, 72), 256, 0, stream>>>(
      seqb, ipwb, xz, nullptr, nullptr, nullptr, nullptr, nullptr, 9216, 1024, 256);
  k_dwconv<<<dim3(2304, 4), 256, 0, stream>>>(xz, c1w, c1b, uAct);
  k_gemm<64, 80, 32, 4, 5><<<dim3(1, 144), 256, 0, stream>>>(uAct, xpw, x_dbl, 9216, 80, 512);
  k_dtproj<<<1152, 256, 0, stream>>>(x_dbl, dtw, dtb, delta);
  k_scan1<<<dim3(2, 4, NCHUNK), 256, 0, stream>>>(delta, uAct, x_dbl, Alog, Sbuf, Sumx);
  k_scan2<<<256, 256, 0, stream>>>(Sbuf, Sumx, Alog);
  k_scan3<<<dim3(2, 4, NCHUNK), 256, 0, stream>>>(delta, uAct, x_dbl, Alog, Sbuf, xz, Dv, ybufb);
  // out_proj: [9216][512] x [256][512]^T -> osc fp32, then transpose to NCHW
  k_mgemm<64, 128, 32, 64, 0><<<dim3(2, 144), 256, 0, stream>>>(
      ybufb, opwb, osc, nullptr, nullptr, nullptr, nullptr, nullptr, 9216, 256, 512);
  k_transpose_out<<<dim3(72, 8, 4), 256, 0, stream>>>(osc, out);
}

// Round 5
// 298.006 us; speedup vs baseline: 2.5063x; 1.1625x over previous
//
#include <hip/hip_runtime.h>
#include <hip/hip_bf16.h>
#include <cmath>

#define L_SEQ 2304
#define NB 4
#define D_IN 64
#define DM 256
#define DI 512
#define DSTATE 32
#define XPN 80
#define NCHUNK 64
#define CHLEN 36   // L_SEQ / NCHUNK

typedef unsigned short u16;
typedef __attribute__((ext_vector_type(8))) short bf16x8;
typedef __attribute__((ext_vector_type(4))) float f32x4;

__device__ __forceinline__ u16 f2b(float f) {
  __hip_bfloat16 h = __float2bfloat16(f);
  return *(u16*)&h;
}

// ---------------- prep ----------------
// x [4][64][48][48] -> xT [4][48*48][64] fp32
__global__ __launch_bounds__(256) void k_transpose_x(const float* __restrict__ x,
                                                     float* __restrict__ xT) {
  int id = blockIdx.x * 256 + threadIdx.x;   // 589824
  int ic = id & 63;
  int sp = id >> 6;
  int b = sp / L_SEQ, pos = sp - b * L_SEQ;
  xT[id] = x[(size_t)(b * D_IN + ic) * L_SEQ + pos];
}

// conv_w [256][64][3][3] -> wTb bf16 [256][576] (k = tap*64+ic)
__global__ __launch_bounds__(256) void k_transpose_w(const float* __restrict__ w,
                                                     u16* __restrict__ wTb) {
  int id = blockIdx.x * 256 + threadIdx.x;   // 147456
  int ic = id & 63;
  int rest = id >> 6;
  int oc = rest / 9, tap = rest - oc * 9;
  wTb[id] = f2b(w[(size_t)(oc * D_IN + ic) * 9 + tap]);
}

// merged fp32->bf16 casts for ipw / opw / xpw
__global__ __launch_bounds__(256) void k_castall(
    const float* __restrict__ a, u16* __restrict__ da, int na,
    const float* __restrict__ b, u16* __restrict__ db, int nb,
    const float* __restrict__ c, u16* __restrict__ dc, int nc) {
  int id = blockIdx.x * 256 + threadIdx.x;
  if (id < na) { da[id] = f2b(a[id]); return; }
  id -= na;
  if (id < nb) { db[id] = f2b(b[id]); return; }
  id -= nb;
  if (id < nc) dc[id] = f2b(c[id]);
}

// im2col: xT fp32 -> im [9216][576] bf16, zero-filled borders
__global__ __launch_bounds__(256) void k_im2col(const float* __restrict__ xT,
                                                u16* __restrict__ im) {
  int id = blockIdx.x * 256 + threadIdx.x;   // 9216*72 = 663552
  int m = id / 72;
  int g8 = id - m * 72;
  int tap = g8 >> 3;
  int ic0 = (g8 & 7) * 8;
  int b = m / L_SEQ; int rem = m - b * L_SEQ;
  int y = rem / 48;  int xx = rem - y * 48;
  int yy = y + tap / 3 - 1, ww = xx + tap % 3 - 1;
  alignas(16) u16 o[8];
  if ((unsigned)yy < 48u && (unsigned)ww < 48u) {
    const float* p = &xT[(((size_t)(b * 48 + yy)) * 48 + ww) * 64 + ic0];
    float4 q0 = *(const float4*)p;
    float4 q1 = *(const float4*)(p + 4);
    o[0] = f2b(q0.x); o[1] = f2b(q0.y); o[2] = f2b(q0.z); o[3] = f2b(q0.w);
    o[4] = f2b(q1.x); o[5] = f2b(q1.y); o[6] = f2b(q1.z); o[7] = f2b(q1.w);
  } else {
#pragma unroll
    for (int i = 0; i < 8; i++) o[i] = 0;
  }
  *(uint4*)&im[(size_t)m * 576 + g8 * 8] = *(uint4*)o;
}

// ---------------- bf16 MFMA GEMM: C[M][N] = A[M][K] * Bw[N][K]^T ----------------
template <int BM, int BN, int WM, int WN, int EPI>
__global__ __launch_bounds__(256) void k_mgemm(
    const u16* __restrict__ A, const u16* __restrict__ Bw,
    float* __restrict__ Cf, u16* __restrict__ Cb,
    const float* __restrict__ g, const float* __restrict__ be,
    const float* __restrict__ mu, const float* __restrict__ va,
    int M, int N, int K) {
  constexpr int BK = 32;
  constexpr int LDR = BK + 8;
  __shared__ u16 As[BM * LDR];
  __shared__ u16 Bs[BN * LDR];
  const int tid = threadIdx.x;
  const int lane = tid & 63;
  const int wid = tid >> 6;
  constexpr int NWN = BN / WN;
  const int wn = (wid % NWN) * WN;
  const int wm = (wid / NWN) * WM;
  const int ln15 = lane & 15;
  const int quad = lane >> 4;
  const int n0 = blockIdx.x * BN;
  const int m0 = blockIdx.y * BM;
  constexpr int TMN = WM / 16, TNN = WN / 16;

  f32x4 acc[TMN][TNN];
#pragma unroll
  for (int i = 0; i < TMN; i++)
#pragma unroll
    for (int j = 0; j < TNN; j++) acc[i][j] = (f32x4){0.f, 0.f, 0.f, 0.f};

  const int srow = tid >> 2;
  const int spart = (tid & 3) * 8;

  for (int k0 = 0; k0 < K; k0 += BK) {
    __syncthreads();
#pragma unroll
    for (int p = 0; p < BM / 64; p++) {
      int row = srow + p * 64;
      uint4 q = *(const uint4*)&A[(size_t)(m0 + row) * K + k0 + spart];
      *(uint4*)&As[row * LDR + spart] = q;
    }
#pragma unroll
    for (int p = 0; p < BN / 64; p++) {
      int row = srow + p * 64;
      uint4 q = *(const uint4*)&Bw[(size_t)(n0 + row) * K + k0 + spart];
      *(uint4*)&Bs[row * LDR + spart] = q;
    }
    __syncthreads();

    bf16x8 af[TMN], bfr[TNN];
#pragma unroll
    for (int i = 0; i < TMN; i++)
      af[i] = *(const bf16x8*)&As[(wm + i * 16 + ln15) * LDR + quad * 8];
#pragma unroll
    for (int j = 0; j < TNN; j++)
      bfr[j] = *(const bf16x8*)&Bs[(wn + j * 16 + ln15) * LDR + quad * 8];
#pragma unroll
    for (int i = 0; i < TMN; i++)
#pragma unroll
      for (int j = 0; j < TNN; j++)
        acc[i][j] = __builtin_amdgcn_mfma_f32_16x16x32_bf16(af[i], bfr[j], acc[i][j], 0, 0, 0);
  }

  if constexpr (EPI == 0) {
#pragma unroll
    for (int i = 0; i < TMN; i++) {
      int mb = m0 + wm + i * 16 + quad * 4;
#pragma unroll
      for (int j = 0; j < TNN; j++) {
        int n = n0 + wn + j * 16 + ln15;
#pragma unroll
        for (int r = 0; r < 4; r++)
          Cf[(size_t)(mb + r) * N + n] = acc[i][j][r];
      }
    }
  } else {
#pragma unroll
    for (int j = 0; j < TNN; j++) {
      int n = n0 + wn + j * 16 + ln15;
      float iv = g[n] * rsqrtf(va[n] + 1e-5f);
      float sh = be[n] - mu[n] * iv;
#pragma unroll
      for (int i = 0; i < TMN; i++) {
        int mb = m0 + wm + i * 16 + quad * 4;
#pragma unroll
        for (int r = 0; r < 4; r++) {
          float v = fmaxf(acc[i][j][r] * iv + sh, 0.f);
          Cb[(size_t)(mb + r) * N + n] = f2b(v);
        }
      }
    }
  }
}

// ---------------- x_proj bf16 MFMA: x_dbl[9216][80] = uActb[9216][512] * xpwb[80][512]^T ----
// BM=64, BN=80 (5 n-tiles), BK=32; 4 waves, wave = 16 rows x 80 cols. grid 144.
__global__ __launch_bounds__(256) void k_xproj(const u16* __restrict__ A,
                                               const u16* __restrict__ Bw,
                                               float* __restrict__ C) {
  constexpr int BK = 32, LDR = 40;
  __shared__ u16 As[64 * LDR];
  __shared__ u16 Bs[80 * LDR];
  const int tid = threadIdx.x;
  const int lane = tid & 63;
  const int wid = tid >> 6;
  const int ln15 = lane & 15;
  const int quad = lane >> 4;
  const int m0 = blockIdx.x * 64;
  const int wm = wid * 16;

  f32x4 acc[5];
#pragma unroll
  for (int j = 0; j < 5; j++) acc[j] = (f32x4){0.f, 0.f, 0.f, 0.f};

  const int srow = tid >> 2;
  const int spart = (tid & 3) * 8;

  for (int k0 = 0; k0 < DI; k0 += BK) {
    __syncthreads();
    *(uint4*)&As[srow * LDR + spart] = *(const uint4*)&A[(size_t)(m0 + srow) * DI + k0 + spart];
    *(uint4*)&Bs[srow * LDR + spart] = *(const uint4*)&Bw[(size_t)srow * DI + k0 + spart];
    if (srow < 16)
      *(uint4*)&Bs[(srow + 64) * LDR + spart] =
          *(const uint4*)&Bw[(size_t)(srow + 64) * DI + k0 + spart];
    __syncthreads();

    bf16x8 af = *(const bf16x8*)&As[(wm + ln15) * LDR + quad * 8];
#pragma unroll
    for (int j = 0; j < 5; j++) {
      bf16x8 bf = *(const bf16x8*)&Bs[(j * 16 + ln15) * LDR + quad * 8];
      acc[j] = __builtin_amdgcn_mfma_f32_16x16x32_bf16(af, bf, acc[j], 0, 0, 0);
    }
  }

#pragma unroll
  for (int j = 0; j < 5; j++) {
    int n = j * 16 + ln15;
    int mb = m0 + wm + quad * 4;
#pragma unroll
    for (int r = 0; r < 4; r++)
      C[(size_t)(mb + r) * XPN + n] = acc[j][r];
  }
}

// ---------------- causal depthwise conv1d (k=4) + bias + SiLU ----------------
// emits fp32 uAct (for scan) and bf16 uActb (for x_proj GEMM)
__global__ __launch_bounds__(256) void k_dwconv(
    const float* __restrict__ xz, const float* __restrict__ w1,
    const float* __restrict__ b1, float* __restrict__ uAct,
    u16* __restrict__ uActb) {
  int l = blockIdx.x;
  int b = blockIdx.y;
  int d = threadIdx.x;
#pragma unroll
  for (int half = 0; half < 2; half++, d += 256) {
    float4 wq = *(const float4*)&w1[d * 4];
    float acc = b1[d];
    if (l >= 3) acc = fmaf(xz[((size_t)(b * L_SEQ + l - 3)) * 1024 + d], wq.x, acc);
    if (l >= 2) acc = fmaf(xz[((size_t)(b * L_SEQ + l - 2)) * 1024 + d], wq.y, acc);
    if (l >= 1) acc = fmaf(xz[((size_t)(b * L_SEQ + l - 1)) * 1024 + d], wq.z, acc);
    acc = fmaf(xz[((size_t)(b * L_SEQ + l)) * 1024 + d], wq.w, acc);
    float sil = acc / (1.f + __expf(-acc));
    size_t idx = ((size_t)(b * L_SEQ + l)) * DI + d;
    uAct[idx] = sil;
    uActb[idx] = f2b(sil);
  }
}

// ---------------- dt_proj + softplus -> delta [B*L][512] ----------------
__global__ __launch_bounds__(256) void k_dtproj(
    const float* __restrict__ x_dbl, const float* __restrict__ dtw,
    const float* __restrict__ dtb, float* __restrict__ delta) {
  __shared__ float xs[8][16];
  int m0 = blockIdx.x * 8;
  int tid = threadIdx.x;
  if (tid < 128) {
    int r = tid >> 4, k = tid & 15;
    xs[r][k] = x_dbl[(size_t)(m0 + r) * XPN + k];
  }
  __syncthreads();
  int n = tid;
#pragma unroll
  for (int half = 0; half < 2; half++, n += 256) {
    float4 w0 = *(const float4*)&dtw[n * 16];
    float4 w1 = *(const float4*)&dtw[n * 16 + 4];
    float4 w2 = *(const float4*)&dtw[n * 16 + 8];
    float4 w3 = *(const float4*)&dtw[n * 16 + 12];
    float bias = dtb[n];
#pragma unroll
    for (int r = 0; r < 8; r++) {
      float4 x0 = *(const float4*)&xs[r][0];
      float4 x1 = *(const float4*)&xs[r][4];
      float4 x2 = *(const float4*)&xs[r][8];
      float4 x3 = *(const float4*)&xs[r][12];
      float s = bias;
      s = fmaf(w0.x, x0.x, s); s = fmaf(w0.y, x0.y, s); s = fmaf(w0.z, x0.z, s); s = fmaf(w0.w, x0.w, s);
      s = fmaf(w1.x, x1.x, s); s = fmaf(w1.y, x1.y, s); s = fmaf(w1.z, x1.z, s); s = fmaf(w1.w, x1.w, s);
      s = fmaf(w2.x, x2.x, s); s = fmaf(w2.y, x2.y, s); s = fmaf(w2.z, x2.z, s); s = fmaf(w2.w, x2.w, s);
      s = fmaf(w3.x, x3.x, s); s = fmaf(w3.y, x3.y, s); s = fmaf(w3.z, x3.z, s); s = fmaf(w3.w, x3.w, s);
      float sp = fmaxf(s, 0.f) + log1pf(expf(-fabsf(s)));
      delta[(size_t)(m0 + r) * DI + n] = sp;
    }
  }
}

// ---------------- selective scan, 3-phase chunked ----------------
__global__ __launch_bounds__(256) void k_scan1(
    const float* __restrict__ delta, const float* __restrict__ uA,
    const float* __restrict__ x_dbl, const float* __restrict__ A_log,
    float* __restrict__ Sbuf, float* __restrict__ Sumx) {
  int d = blockIdx.x * 256 + threadIdx.x;
  int b = blockIdx.y;
  int c = blockIdx.z;

  float a[DSTATE];
#pragma unroll
  for (int q = 0; q < 8; q++) {
    float4 av = *(const float4*)&A_log[d * DSTATE + 4 * q];
    a[4 * q + 0] = -__expf(av.x); a[4 * q + 1] = -__expf(av.y);
    a[4 * q + 2] = -__expf(av.z); a[4 * q + 3] = -__expf(av.w);
  }
  float s[DSTATE];
#pragma unroll
  for (int n = 0; n < DSTATE; n++) s[n] = 0.f;
  float sumx = 0.f;

  int t0 = c * CHLEN;
  const float* dp = delta + ((size_t)(b * L_SEQ + t0)) * DI + d;
  const float* up = uA + ((size_t)(b * L_SEQ + t0)) * DI + d;
  const float* bp = x_dbl + ((size_t)(b * L_SEQ + t0)) * XPN + 16;

#pragma unroll 4
  for (int t = 0; t < CHLEN; t++) {
    float xw = *dp; float uu = *up;
    float4 Bq[8];
#pragma unroll
    for (int q = 0; q < 8; q++) Bq[q] = *(const float4*)(bp + 4 * q);
    dp += DI; up += DI; bp += XPN;
    float du = xw * uu;
    sumx += xw;
#pragma unroll
    for (int q = 0; q < 8; q++) {
      s[4 * q + 0] = fmaf(s[4 * q + 0], __expf(xw * a[4 * q + 0]), du * Bq[q].x);
      s[4 * q + 1] = fmaf(s[4 * q + 1], __expf(xw * a[4 * q + 1]), du * Bq[q].y);
      s[4 * q + 2] = fmaf(s[4 * q + 2], __expf(xw * a[4 * q + 2]), du * Bq[q].z);
      s[4 * q + 3] = fmaf(s[4 * q + 3], __expf(xw * a[4 * q + 3]), du * Bq[q].w);
    }
  }

  float* sb = Sbuf + ((size_t)c * 65536) + ((size_t)(b * DI + d)) * DSTATE;
#pragma unroll
  for (int q = 0; q < 8; q++) {
    float4 v = {s[4 * q], s[4 * q + 1], s[4 * q + 2], s[4 * q + 3]};
    *(float4*)(sb + 4 * q) = v;
  }
  Sumx[c * (NB * DI) + b * DI + d] = sumx;
}

__global__ __launch_bounds__(256) void k_scan2(float* __restrict__ Sbuf,
                                               const float* __restrict__ Sumx,
                                               const float* __restrict__ A_log) {
  int gidx = blockIdx.x * 256 + threadIdx.x;
  int bd = gidx >> 5;
  int d = bd & (DI - 1);
  int n = gidx & 31;
  float a = -__expf(A_log[d * DSTATE + n]);
  float carry = 0.f;
  for (int c = 0; c < NCHUNK; c++) {
    float s = Sbuf[(size_t)c * 65536 + gidx];
    float p = __expf(a * Sumx[c * (NB * DI) + bd]);
    Sbuf[(size_t)c * 65536 + gidx] = carry;
    carry = fmaf(p, carry, s);
  }
}

__global__ __launch_bounds__(256) void k_scan3(
    const float* __restrict__ delta, const float* __restrict__ uA,
    const float* __restrict__ x_dbl, const float* __restrict__ A_log,
    const float* __restrict__ Sbuf, const float* __restrict__ xz,
    const float* __restrict__ Dv, u16* __restrict__ y) {
  int d = blockIdx.x * 256 + threadIdx.x;
  int b = blockIdx.y;
  int c = blockIdx.z;

  float a[DSTATE];
#pragma unroll
  for (int q = 0; q < 8; q++) {
    float4 av = *(const float4*)&A_log[d * DSTATE + 4 * q];
    a[4 * q + 0] = -__expf(av.x); a[4 * q + 1] = -__expf(av.y);
    a[4 * q + 2] = -__expf(av.z); a[4 * q + 3] = -__expf(av.w);
  }
  float s[DSTATE];
  const float* sb = Sbuf + ((size_t)c * 65536) + ((size_t)(b * DI + d)) * DSTATE;
#pragma unroll
  for (int q = 0; q < 8; q++) {
    float4 v = *(const float4*)(sb + 4 * q);
    s[4 * q] = v.x; s[4 * q + 1] = v.y; s[4 * q + 2] = v.z; s[4 * q + 3] = v.w;
  }
  float Dd = Dv[d];

  int t0 = c * CHLEN;
  const float* dp = delta + ((size_t)(b * L_SEQ + t0)) * DI + d;
  const float* up = uA + ((size_t)(b * L_SEQ + t0)) * DI + d;
  const float* bp = x_dbl + ((size_t)(b * L_SEQ + t0)) * XPN + 16;
  const float* cp = x_dbl + ((size_t)(b * L_SEQ + t0)) * XPN + 48;
  const float* zp = xz + ((size_t)(b * L_SEQ + t0)) * 1024 + 512 + d;
  u16* yp = y + ((size_t)(b * L_SEQ + t0)) * DI + d;

#pragma unroll 4
  for (int t = 0; t < CHLEN; t++) {
    float xw = *dp; float uu = *up; float zv = *zp;
    float4 Bq[8], Cq[8];
#pragma unroll
    for (int q = 0; q < 8; q++) Bq[q] = *(const float4*)(bp + 4 * q);
#pragma unroll
    for (int q = 0; q < 8; q++) Cq[q] = *(const float4*)(cp + 4 * q);
    dp += DI; up += DI; bp += XPN; cp += XPN; zp += 1024;
    float du = xw * uu;
    float yv = 0.f;
#pragma unroll
    for (int q = 0; q < 8; q++) {
      s[4 * q + 0] = fmaf(s[4 * q + 0], __expf(xw * a[4 * q + 0]), du * Bq[q].x);
      s[4 * q + 1] = fmaf(s[4 * q + 1], __expf(xw * a[4 * q + 1]), du * Bq[q].y);
      s[4 * q + 2] = fmaf(s[4 * q + 2], __expf(xw * a[4 * q + 2]), du * Bq[q].z);
      s[4 * q + 3] = fmaf(s[4 * q + 3], __expf(xw * a[4 * q + 3]), du * Bq[q].w);
      yv = fmaf(s[4 * q + 0], Cq[q].x, yv);
      yv = fmaf(s[4 * q + 1], Cq[q].y, yv);
      yv = fmaf(s[4 * q + 2], Cq[q].z, yv);
      yv = fmaf(s[4 * q + 3], Cq[q].w, yv);
    }
    float out = (yv + uu * Dd) * (zv / (1.f + __expf(-zv)));
    *yp = f2b(out);
    yp += DI;
  }
}

// ---------------- final transpose: [B][L][256] -> [B][256][L] ----------------
__global__ __launch_bounds__(256) void k_transpose_out(const float* __restrict__ src,
                                                       float* __restrict__ dst) {
  __shared__ float tile[32][33];
  int l0 = blockIdx.x * 32;
  int n0 = blockIdx.y * 32;
  int b = blockIdx.z;
  int tx = threadIdx.x & 31;
  int ty = threadIdx.x >> 5;
#pragma unroll
  for (int r = ty; r < 32; r += 8)
    tile[r][tx] = src[((size_t)(b * L_SEQ + l0 + r)) * DM + n0 + tx];
  __syncthreads();
#pragma unroll
  for (int r = ty; r < 32; r += 8)
    dst[((size_t)(b * DM + n0 + r)) * L_SEQ + l0 + tx] = tile[tx][r];
}

// ---------------- launcher ----------------
extern "C" void kernel_launch(void* const* d_in, const int* in_sizes, int n_in,
                              void* d_out, int out_size, void* d_ws, size_t ws_size,
                              hipStream_t stream) {
  const float* x     = (const float*)d_in[0];
  const float* cw    = (const float*)d_in[1];
  const float* gamma = (const float*)d_in[2];
  const float* beta  = (const float*)d_in[3];
  const float* mean  = (const float*)d_in[4];
  const float* var   = (const float*)d_in[5];
  const float* ipw   = (const float*)d_in[6];
  const float* c1w   = (const float*)d_in[7];
  const float* c1b   = (const float*)d_in[8];
  const float* xpw   = (const float*)d_in[9];
  const float* dtw   = (const float*)d_in[10];
  const float* dtb   = (const float*)d_in[11];
  const float* Alog  = (const float*)d_in[12];
  const float* Dv    = (const float*)d_in[13];
  const float* opw   = (const float*)d_in[14];
  float* out = (float*)d_out;

  float* ws = (float*)d_ws;
  size_t o = 0;
  u16*   ybufb = (u16*)(ws + o);   o += (size_t)NB * L_SEQ * DI / 2;   // bf16 [9216][512]
  float* xz    = ws + o;           o += (size_t)NB * L_SEQ * 1024;
  float* uAct  = ws + o;           o += (size_t)NB * L_SEQ * DI;
  u16*   uActb = (u16*)(ws + o);   o += (size_t)NB * L_SEQ * DI / 2;   // bf16 [9216][512]
  float* x_dbl = ws + o;           o += (size_t)NB * L_SEQ * XPN;
  float* delta = ws + o;           o += (size_t)NB * L_SEQ * DI;       // also out_proj fp32 scratch
  float* xT    = ws + o;           o += (size_t)NB * L_SEQ * D_IN;
  float* Sbuf  = ws + o;           o += (size_t)NCHUNK * 65536;        // also im2col bf16 scratch
  float* Sumx  = ws + o;           o += (size_t)NCHUNK * NB * DI;
  u16*   seqb  = (u16*)(ws + o);   o += (size_t)NB * L_SEQ * DM / 2;   // bf16 [9216][256]
  u16*   wTb   = (u16*)(ws + o);   o += (size_t)DM * 9 * D_IN / 2;
  u16*   ipwb  = (u16*)(ws + o);   o += (size_t)2 * DI * DM / 2;
  u16*   opwb  = (u16*)(ws + o);   o += (size_t)DM * DI / 2;
  u16*   xpwb  = (u16*)(ws + o);   o += (size_t)XPN * DI / 2;
  u16*   im2c  = (u16*)Sbuf;                                           // [9216][576] bf16
  float* osc   = delta;                                                // [9216][256] fp32

  k_transpose_x<<<2304, 256, 0, stream>>>(x, xT);
  k_transpose_w<<<576, 256, 0, stream>>>(cw, wTb);
  k_castall<<<1696, 256, 0, stream>>>(ipw, ipwb, 2 * DI * DM,
                                      opw, opwb, DM * DI,
                                      xpw, xpwb, XPN * DI);
  k_im2col<<<2592, 256, 0, stream>>>(xT, im2c);
  // conv3x3+BN+ReLU: [9216][576] x [256][576]^T -> seqb bf16
  k_mgemm<64, 128, 32, 64, 1><<<dim3(2, 144), 256, 0, stream>>>(
      im2c, wTb, nullptr, seqb, gamma, beta, mean, var, 9216, 256, 576);
  // in_proj: [9216][256] x [1024][256]^T -> xz fp32
  k_mgemm<128, 128, 64, 64, 0><<<dim3(8, 72), 256, 0, stream>>>(
      seqb, ipwb, xz, nullptr, nullptr, nullptr, nullptr, nullptr, 9216, 1024, 256);
  k_dwconv<<<dim3(2304, 4), 256, 0, stream>>>(xz, c1w, c1b, uAct, uActb);
  k_xproj<<<144, 256, 0, stream>>>(uActb, xpwb, x_dbl);
  k_dtproj<<<1152, 256, 0, stream>>>(x_dbl, dtw, dtb, delta);
  k_scan1<<<dim3(2, 4, NCHUNK), 256, 0, stream>>>(delta, uAct, x_dbl, Alog, Sbuf, Sumx);
  k_scan2<<<256, 256, 0, stream>>>(Sbuf, Sumx, Alog);
  k_scan3<<<dim3(2, 4, NCHUNK), 256, 0, stream>>>(delta, uAct, x_dbl, Alog, Sbuf, xz, Dv, ybufb);
  // out_proj: [9216][512] x [256][512]^T -> osc fp32, then transpose to NCHW
  k_mgemm<64, 128, 32, 64, 0><<<dim3(2, 144), 256, 0, stream>>>(
      ybufb, opwb, osc, nullptr, nullptr, nullptr, nullptr, nullptr, 9216, 256, 512);
  k_transpose_out<<<dim3(72, 8, 4), 256, 0, stream>>>(osc, out);
}